// Round 6
// baseline (1048.625 us; speedup 1.0000x reference)
//
#include <hip/hip_runtime.h>
#include <stdint.h>

#define BATCH 128
#define NAT   128
#define DIM   128
#define CP    17
#define MAXIT 20
#define STEP  0.2f      // 2 * R_LR
#define LMD   0.005f
#define NGRAD 450

typedef short bf16x8 __attribute__((ext_vector_type(8)));   // 8 bf16 (4 VGPR)
typedef float f32x16 __attribute__((ext_vector_type(16)));  // 32x32 C/D

#define SZ_RP (BATCH*CP*CP*NAT)     // 4,734,976 elems
#define SZ_RS (BATCH*DIM*DIM)       // 2,097,152 elems
// workspace byte offsets (all 16B-aligned)
#define O_RPH  0
#define O_RPL  (O_RPH + SZ_RP*2)
#define O_RSH  (O_RPL + SZ_RP*2)
#define O_RSL  (O_RSH + SZ_RS*2)
#define O_W2H  (O_RSL + SZ_RS*2)
#define O_W2L  (O_W2H + 64*512*2)
#define O_WTH  (O_W2L + 64*512*2)
#define O_WTL  (O_WTH + 128*256*2)
#define O_PART (O_WTL + 128*256*2)
#define O_FLAG (O_PART + 2048*4)

// split fp32 -> hi/lo bf16 (RNE); hi+lo carries ~16 mantissa bits
__device__ __forceinline__ void split2(float x, ushort& h, ushort& l) {
    uint32_t u = __float_as_uint(x);
    uint32_t hr = (u + 0x7FFFu + ((u >> 16) & 1u)) >> 16;
    h = (ushort)hr;
    float r = x - __uint_as_float(hr << 16);
    uint32_t u2 = __float_as_uint(r);
    l = (ushort)((u2 + 0x7FFFu + ((u2 >> 16) & 1u)) >> 16);
}
__device__ __forceinline__ float us2f(ushort u) {
    return __uint_as_float(((uint32_t)u) << 16);
}
__device__ __forceinline__ uint pk(ushort a, ushort b) {
    return (uint)a | ((uint)b << 16);
}

__global__ void kzero(uint4* __restrict__ rp, int* __restrict__ flags) {
    int i = blockIdx.x * 256 + threadIdx.x;
    rp[i] = uint4{0u, 0u, 0u, 0u};   // covers rpad hi+lo planes
    if (blockIdx.x == 0 && threadIdx.x < 32) flags[threadIdx.x] = 0;
}

// WtT = W layout [n][256]; W2T[uv][ij*128+n]; both as hi/lo bf16 planes
__global__ void kprep(const float* __restrict__ W,
                      ushort* __restrict__ wth, ushort* __restrict__ wtl,
                      ushort* __restrict__ w2h, ushort* __restrict__ w2l) {
    int tid = blockIdx.x * 256 + threadIdx.x;   // 32768
    int n = tid >> 8, kk = tid & 255;
    ushort h, l; split2(W[tid], h, l);
    wth[tid] = h; wtl[tid] = l;
    int kx = kk >> 4, ky = kk & 15;
    int uv = (kx & 7) * 8 + (ky & 7);
    int k2 = ((kx >> 3) * 2 + (ky >> 3)) * 128 + n;
    w2h[uv * 512 + k2] = h; w2l[uv * 512 + k2] = l;
}

// t=0 shortcut: R==0 -> resid = img (split to bf16 hi/lo planes)
__global__ void kinit0(const float* __restrict__ img,
                       ushort* __restrict__ rsh, ushort* __restrict__ rsl) {
    int t8 = (blockIdx.x * 256 + threadIdx.x) * 8;
    uint hw[4], lw[4];
#pragma unroll
    for (int v = 0; v < 2; ++v) {
        float4 im = *(const float4*)&img[t8 + v * 4];
        ushort h0,l0,h1,l1,h2,l2,h3,l3;
        split2(im.x, h0, l0); split2(im.y, h1, l1);
        split2(im.z, h2, l2); split2(im.w, h3, l3);
        hw[v*2+0] = pk(h0,h1); hw[v*2+1] = pk(h2,h3);
        lw[v*2+0] = pk(l0,l1); lw[v*2+1] = pk(l2,l3);
    }
    *(uint4*)&rsh[t8] = uint4{hw[0],hw[1],hw[2],hw[3]};
    *(uint4*)&rsl[t8] = uint4{lw[0],lw[1],lw[2],lw[3]};
}

// conv_t(R) as MFMA GEMM: C[m=cell, uv=64] = Rpad[m,K=512] x W2T^T.
// t>=1: gate from partials first; resid = img - C via LDS-staged coalesced write.
// t<0: final fp32 reconstruction to outp.
__global__ __launch_bounds__(256) void kconvt(
    const ushort* __restrict__ rph, const ushort* __restrict__ rpl,
    const ushort* __restrict__ w2h, const ushort* __restrict__ w2l,
    const float* __restrict__ img, float* __restrict__ outp,
    ushort* __restrict__ rsh, ushort* __restrict__ rsl,
    const float* __restrict__ partials, int* __restrict__ flags, int t)
{
    const int tid = threadIdx.x;
    if (t >= 1) {   // convergence gate (deterministic, same in every block)
        __shared__ float red0[16];
        __shared__ int sgate;
        float d2 = 0.f, r2 = 0.f;
        for (int i = tid; i < NGRAD; i += 256) { d2 += partials[i]; r2 += partials[1024 + i]; }
        for (int off = 32; off; off >>= 1) { d2 += __shfl_down(d2, off, 64); r2 += __shfl_down(r2, off, 64); }
        int w = tid >> 6, l = tid & 63;
        if (l == 0) { red0[w] = d2; red0[8 + w] = r2; }
        __syncthreads();
        if (tid == 0) {
            float td = red0[0] + red0[1] + red0[2] + red0[3];
            float tr = red0[8] + red0[9] + red0[10] + red0[11];
            sgate = flags[t - 1] | ((td < 1e-4f * tr) ? 1 : 0);
            if (blockIdx.x == 0) flags[t] = sgate;
        }
        __syncthreads();
        if (sgate) return;
    }

    __shared__ uint4 lds[2048];   // Ahi[512] Alo[512] Bhi[512] Blo[512]
    const int bx = blockIdx.x;
    const int bid = ((bx & 7) << 6) | (bx >> 3);   // XCD swizzle, 512%8==0
    const int m0 = bid * 64;
    const int ml = tid >> 2, q = tid & 3;
    const int lane = tid & 63, wv = tid >> 6, wm = wv >> 1, wn = wv & 1, g = lane >> 5;
    const int mm = m0 + ml;
    const int b_ = mm >> 8, cell = mm & 255, px0 = cell >> 4, py0 = cell & 15;

    uint4 pa0, pa1, pb0, pb1, pc0, pc1, pd0, pd1;
    auto load_chunk = [&](int kc) {
        const int ij = kc >> 1, ic = ij >> 1, jc = ij & 1;
        const int nb = (kc & 1) * 64;
        const int off = ((b_ * CP + px0 + 1 - ic) * CP + py0 + 1 - jc) * NAT + nb + q * 16;
        pa0 = ((const uint4*)(rph + off))[0]; pa1 = ((const uint4*)(rph + off))[1];
        pb0 = ((const uint4*)(rpl + off))[0]; pb1 = ((const uint4*)(rpl + off))[1];
        const int bo = ml * 512 + kc * 64 + q * 16;
        pc0 = ((const uint4*)(w2h + bo))[0]; pc1 = ((const uint4*)(w2h + bo))[1];
        pd0 = ((const uint4*)(w2l + bo))[0]; pd1 = ((const uint4*)(w2l + bo))[1];
    };
    auto write_chunk = [&]() {
        int e0 = (q * 2) ^ (ml & 7), e1 = (q * 2 + 1) ^ (ml & 7);
        lds[       ml * 8 + e0] = pa0; lds[       ml * 8 + e1] = pa1;
        lds[512  + ml * 8 + e0] = pb0; lds[512  + ml * 8 + e1] = pb1;
        lds[1024 + ml * 8 + e0] = pc0; lds[1024 + ml * 8 + e1] = pc1;
        lds[1536 + ml * 8 + e0] = pd0; lds[1536 + ml * 8 + e1] = pd1;
    };

    f32x16 acc = {};
    const int arow = wm * 32 + (lane & 31);
    const int brow = wn * 32 + (lane & 31);
    const int ax = lane & 7;
    load_chunk(0); write_chunk(); __syncthreads();
    for (int kc = 0;; ++kc) {
        if (kc < 7) load_chunk(kc + 1);
#pragma unroll
        for (int ks = 0; ks < 4; ++ks) {
            int un = (ks * 2 + g) ^ ax;
            bf16x8 Ah = __builtin_bit_cast(bf16x8, lds[       arow * 8 + un]);
            bf16x8 Al = __builtin_bit_cast(bf16x8, lds[512  + arow * 8 + un]);
            bf16x8 Bh = __builtin_bit_cast(bf16x8, lds[1024 + brow * 8 + un]);
            bf16x8 Bl = __builtin_bit_cast(bf16x8, lds[1536 + brow * 8 + un]);
            acc = __builtin_amdgcn_mfma_f32_32x32x16_bf16(Ah, Bh, acc, 0, 0, 0);
            acc = __builtin_amdgcn_mfma_f32_32x32x16_bf16(Ah, Bl, acc, 0, 0, 0);
            acc = __builtin_amdgcn_mfma_f32_32x32x16_bf16(Al, Bh, acc, 0, 0, 0);
        }
        if (kc == 7) break;
        __syncthreads(); write_chunk(); __syncthreads();
    }

    // ---- epilogue: stage 32x128 image slab in LDS, write coalesced ----
    __syncthreads();                    // all fragment reads done
    float* ldsO = (float*)lds;          // [32][129] fp32 = 16.5 KB
    const int uvx = wn * 32 + (lane & 31);
    const int uu = uvx >> 3, vv = uvx & 7;
#pragma unroll
    for (int r = 0; r < 16; ++r) {
        int mr = m0 + wm * 32 + (r & 3) + 8 * (r >> 2) + 4 * g;
        int cl = mr & 255;
        int rowl = ((cl >> 4) & 3) * 8 + uu;
        int col = (cl & 15) * 8 + vv;
        ldsO[rowl * 129 + col] = acc[r];
    }
    __syncthreads();
    const int b0 = m0 >> 8;                  // batch
    const int x0 = ((m0 & 255) >> 4) * 8;    // first image row of slab
    const int row = tid >> 3, c0 = (tid & 7) * 16;
    const int base = b0 * DIM * DIM + (x0 + row) * DIM + c0;
    const float* lrow = &ldsO[row * 129 + c0];
    if (t >= 0) {
#pragma unroll
        for (int half = 0; half < 2; ++half) {
            uint hw[4], lw[4];
#pragma unroll
            for (int v = 0; v < 2; ++v) {
                int o = half * 8 + v * 4;
                float4 im = *(const float4*)&img[base + o];
                ushort h0,l0,h1,l1,h2,l2,h3,l3;
                split2(im.x - lrow[o + 0], h0, l0);
                split2(im.y - lrow[o + 1], h1, l1);
                split2(im.z - lrow[o + 2], h2, l2);
                split2(im.w - lrow[o + 3], h3, l3);
                hw[v*2+0] = pk(h0,h1); hw[v*2+1] = pk(h2,h3);
                lw[v*2+0] = pk(l0,l1); lw[v*2+1] = pk(l2,l3);
            }
            *(uint4*)&rsh[base + half * 8] = uint4{hw[0],hw[1],hw[2],hw[3]};
            *(uint4*)&rsl[base + half * 8] = uint4{lw[0],lw[1],lw[2],lw[3]};
        }
    } else {
#pragma unroll
        for (int v = 0; v < 4; ++v) {
            int o = v * 4;
            *(float4*)&outp[base + o] = float4{lrow[o], lrow[o+1], lrow[o+2], lrow[o+3]};
        }
    }
}

// grad MFMA GEMM g[m=64 cells, n=128 atoms] = residpatch[m,K=256] x WtT^T,
// fused SGD + soft-threshold + R(hi/lo) update + norm partials (plain stores)
__global__ __launch_bounds__(256) void kgrad(
    const ushort* __restrict__ rsh, const ushort* __restrict__ rsl,
    const ushort* __restrict__ wth, const ushort* __restrict__ wtl,
    ushort* __restrict__ rph, ushort* __restrict__ rpl,
    float* __restrict__ partials, const int* __restrict__ flags, int t)
{
    if (flags[t]) return;
    __shared__ uint4 lds[3072];   // Ahi[512] Alo[512] Bhi[1024] Blo[1024] = 48 KB
    __shared__ float red0[16];
    const int tid = threadIdx.x;
    const int bx = blockIdx.x;
    const int xcd = bx & 7;   // bijective XCD swizzle for nwg=450 (q=56,r=2)
    const int bid = (xcd < 2 ? xcd * 57 : 114 + (xcd - 2) * 56) + (bx >> 3);
    const int m0 = bid * 64;
    const int lane = tid & 63, wv = tid >> 6, wm = wv >> 1, wn = wv & 1, g = lane >> 5;

    // A staging: cellA=(tid>>1)&63, kyh=tid&1, kxh=tid>>7 (2 kx per i-iter)
    const int cA = (tid >> 1) & 63, kyh = tid & 1, kxh = tid >> 7;
    const int mA = m0 + cA;
    const int bA = mA / 225, remA = mA % 225, pxA = remA / 15, pyA = remA % 15;
    // B staging: nB=tid>>3 (+32 per i), uB=tid&7
    const int nB = tid >> 3, uB = tid & 7;

    uint4 aH[2], aL[2], bH[4], bL[4];
    auto load_chunk = [&](int kc) {
#pragma unroll
        for (int i = 0; i < 2; ++i) {
            int kx = kc * 4 + i * 2 + kxh;
            int off = bA * (DIM * DIM) + (8 * pxA + kx) * DIM + 8 * pyA + kyh * 8;
            aH[i] = *(const uint4*)&rsh[off];
            aL[i] = *(const uint4*)&rsl[off];
        }
#pragma unroll
        for (int i = 0; i < 4; ++i) {
            int off = (i * 32 + nB) * 256 + kc * 64 + uB * 8;
            bH[i] = *(const uint4*)&wth[off];
            bL[i] = *(const uint4*)&wtl[off];
        }
    };
    auto write_chunk = [&]() {
#pragma unroll
        for (int i = 0; i < 2; ++i) {
            int u = i * 4 + kxh * 2 + kyh;          // k-unit 0..7
            int e = u ^ (cA & 7);
            lds[      cA * 8 + e] = aH[i];
            lds[512 + cA * 8 + e] = aL[i];
        }
#pragma unroll
        for (int i = 0; i < 4; ++i) {
            int n = i * 32 + nB;
            int e = uB ^ (n & 7);
            lds[1024 + n * 8 + e] = bH[i];
            lds[2048 + n * 8 + e] = bL[i];
        }
    };

    f32x16 acc0 = {}, acc1 = {};
    const int arow = wm * 32 + (lane & 31);
    const int br0 = wn * 64 + (lane & 31);
    const int br1 = br0 + 32;
    const int ax = lane & 7;
    load_chunk(0); write_chunk(); __syncthreads();
    for (int kc = 0;; ++kc) {
        if (kc < 3) load_chunk(kc + 1);
#pragma unroll
        for (int ks = 0; ks < 4; ++ks) {
            int un = (ks * 2 + g) ^ ax;
            bf16x8 Ah = __builtin_bit_cast(bf16x8, lds[      arow * 8 + un]);
            bf16x8 Al = __builtin_bit_cast(bf16x8, lds[512 + arow * 8 + un]);
            bf16x8 B0h = __builtin_bit_cast(bf16x8, lds[1024 + br0 * 8 + un]);
            bf16x8 B0l = __builtin_bit_cast(bf16x8, lds[2048 + br0 * 8 + un]);
            acc0 = __builtin_amdgcn_mfma_f32_32x32x16_bf16(Ah, B0h, acc0, 0, 0, 0);
            acc0 = __builtin_amdgcn_mfma_f32_32x32x16_bf16(Ah, B0l, acc0, 0, 0, 0);
            acc0 = __builtin_amdgcn_mfma_f32_32x32x16_bf16(Al, B0h, acc0, 0, 0, 0);
            bf16x8 B1h = __builtin_bit_cast(bf16x8, lds[1024 + br1 * 8 + un]);
            bf16x8 B1l = __builtin_bit_cast(bf16x8, lds[2048 + br1 * 8 + un]);
            acc1 = __builtin_amdgcn_mfma_f32_32x32x16_bf16(Ah, B1h, acc1, 0, 0, 0);
            acc1 = __builtin_amdgcn_mfma_f32_32x32x16_bf16(Ah, B1l, acc1, 0, 0, 0);
            acc1 = __builtin_amdgcn_mfma_f32_32x32x16_bf16(Al, B1h, acc1, 0, 0, 0);
        }
        if (kc == 3) break;
        __syncthreads(); write_chunk(); __syncthreads();
    }

    float d2 = 0.f, r2 = 0.f;
#pragma unroll
    for (int nf = 0; nf < 2; ++nf) {
        int nn = wn * 64 + nf * 32 + (lane & 31);
#pragma unroll
        for (int r = 0; r < 16; ++r) {
            float a = nf ? acc1[r] : acc0[r];
            int mr = m0 + wm * 32 + (r & 3) + 8 * (r >> 2) + 4 * g;
            int bb = mr / 225, rm = mr % 225, pxx = rm / 15, pyy = rm % 15;
            int idx = ((bb * CP + pxx + 1) * CP + pyy + 1) * NAT + nn;
            float rold = us2f(rph[idx]) + us2f(rpl[idx]);
            float v = fmaf(STEP, a, rold);
            float st = fmaxf(v - LMD, 0.f) - fmaxf(-v - LMD, 0.f);
            float df = st - rold;
            d2 += df * df; r2 += rold * rold;
            ushort h, l; split2(st, h, l);
            rph[idx] = h; rpl[idx] = l;
        }
    }
    for (int off = 32; off; off >>= 1) { d2 += __shfl_down(d2, off, 64); r2 += __shfl_down(r2, off, 64); }
    int w = tid >> 6, l = tid & 63;
    if (l == 0) { red0[w] = d2; red0[8 + w] = r2; }
    __syncthreads();
    if (tid == 0) {
        float td = red0[0] + red0[1] + red0[2] + red0[3];
        float tr = red0[8] + red0[9] + red0[10] + red0[11];
        partials[bid] = td;
        partials[1024 + bid] = tr;
    }
}

extern "C" void kernel_launch(void* const* d_in, const int* in_sizes, int n_in,
                              void* d_out, int out_size, void* d_ws, size_t ws_size,
                              hipStream_t stream) {
    const float* img = (const float*)d_in[0];
    const float* W   = (const float*)d_in[1];
    char* ws = (char*)d_ws;
    ushort* rph = (ushort*)(ws + O_RPH);
    ushort* rpl = (ushort*)(ws + O_RPL);
    ushort* rsh = (ushort*)(ws + O_RSH);
    ushort* rsl = (ushort*)(ws + O_RSL);
    ushort* w2h = (ushort*)(ws + O_W2H);
    ushort* w2l = (ushort*)(ws + O_W2L);
    ushort* wth = (ushort*)(ws + O_WTH);
    ushort* wtl = (ushort*)(ws + O_WTL);
    float* partials = (float*)(ws + O_PART);
    int*   flags    = (int*)(ws + O_FLAG);
    float* outp = (float*)d_out;

    kzero<<<4624, 256, 0, stream>>>((uint4*)(ws + O_RPH), flags);
    kprep<<<128, 256, 0, stream>>>(W, wth, wtl, w2h, w2l);
    kinit0<<<1024, 256, 0, stream>>>(img, rsh, rsl);            // t=0: resid = img
    kgrad<<<450, 256, 0, stream>>>(rsh, rsl, wth, wtl, rph, rpl, partials, flags, 0);
    for (int t = 1; t < MAXIT; ++t) {
        kconvt<<<512, 256, 0, stream>>>(rph, rpl, w2h, w2l, img, nullptr, rsh, rsl, partials, flags, t);
        kgrad<<<450, 256, 0, stream>>>(rsh, rsl, wth, wtl, rph, rpl, partials, flags, t);
    }
    kconvt<<<512, 256, 0, stream>>>(rph, rpl, w2h, w2l, img, outp, rsh, rsl, partials, flags, -1);
}

// Round 7
// 652.675 us; speedup vs baseline: 1.6067x; 1.6067x over previous
//
#include <hip/hip_runtime.h>
#include <stdint.h>

#define BATCH 128
#define NAT   128
#define DIM   128
#define CP    17
#define MAXIT 20
#define STEP  0.2f      // 2 * R_LR
#define LMD   0.005f
#define NGRAD 900

typedef short bf16x8 __attribute__((ext_vector_type(8)));   // 8 bf16 (4 VGPR)
typedef float f32x16 __attribute__((ext_vector_type(16)));  // 32x32 C/D

#define SZ_RP (BATCH*CP*CP*NAT)     // 4,734,976 elems
#define SZ_RS (BATCH*DIM*DIM)       // 2,097,152 elems
// workspace byte offsets (all 16B-aligned)
#define O_RPH  0
#define O_RPL  (O_RPH + SZ_RP*2)
#define O_RSH  (O_RPL + SZ_RP*2)
#define O_RSL  (O_RSH + SZ_RS*2)
#define O_W2H  (O_RSL + SZ_RS*2)
#define O_W2L  (O_W2H + 64*512*2)
#define O_WTH  (O_W2L + 64*512*2)
#define O_WTL  (O_WTH + 128*256*2)
#define O_PART (O_WTL + 128*256*2)
#define O_FLAG (O_PART + 2048*4)

// split fp32 -> hi/lo bf16 (RNE); hi+lo carries ~16 mantissa bits
__device__ __forceinline__ void split2(float x, ushort& h, ushort& l) {
    uint32_t u = __float_as_uint(x);
    uint32_t hr = (u + 0x7FFFu + ((u >> 16) & 1u)) >> 16;
    h = (ushort)hr;
    float r = x - __uint_as_float(hr << 16);
    uint32_t u2 = __float_as_uint(r);
    l = (ushort)((u2 + 0x7FFFu + ((u2 >> 16) & 1u)) >> 16);
}
__device__ __forceinline__ float us2f(ushort u) {
    return __uint_as_float(((uint32_t)u) << 16);
}
__device__ __forceinline__ uint pk(ushort a, ushort b) {
    return (uint)a | ((uint)b << 16);
}

__global__ void kzero(uint4* __restrict__ rp, int* __restrict__ flags) {
    int i = blockIdx.x * 256 + threadIdx.x;
    rp[i] = uint4{0u, 0u, 0u, 0u};   // covers rpad hi+lo planes
    if (blockIdx.x == 0 && threadIdx.x < 32) flags[threadIdx.x] = 0;
}

// WtT = W layout [n][256]; W2T[uv][ij*128+n]; both as hi/lo bf16 planes
__global__ void kprep(const float* __restrict__ W,
                      ushort* __restrict__ wth, ushort* __restrict__ wtl,
                      ushort* __restrict__ w2h, ushort* __restrict__ w2l) {
    int tid = blockIdx.x * 256 + threadIdx.x;   // 32768
    int n = tid >> 8, kk = tid & 255;
    ushort h, l; split2(W[tid], h, l);
    wth[tid] = h; wtl[tid] = l;
    int kx = kk >> 4, ky = kk & 15;
    int uv = (kx & 7) * 8 + (ky & 7);
    int k2 = ((kx >> 3) * 2 + (ky >> 3)) * 128 + n;
    w2h[uv * 512 + k2] = h; w2l[uv * 512 + k2] = l;
}

// t=0 shortcut: R==0 -> resid = img (split to bf16 hi/lo planes)
__global__ void kinit0(const float* __restrict__ img,
                       ushort* __restrict__ rsh, ushort* __restrict__ rsl) {
    int t8 = (blockIdx.x * 256 + threadIdx.x) * 8;
    uint hw[4], lw[4];
#pragma unroll
    for (int v = 0; v < 2; ++v) {
        float4 im = *(const float4*)&img[t8 + v * 4];
        ushort h0,l0,h1,l1,h2,l2,h3,l3;
        split2(im.x, h0, l0); split2(im.y, h1, l1);
        split2(im.z, h2, l2); split2(im.w, h3, l3);
        hw[v*2+0] = pk(h0,h1); hw[v*2+1] = pk(h2,h3);
        lw[v*2+0] = pk(l0,l1); lw[v*2+1] = pk(l2,l3);
    }
    *(uint4*)&rsh[t8] = uint4{hw[0],hw[1],hw[2],hw[3]};
    *(uint4*)&rsl[t8] = uint4{lw[0],lw[1],lw[2],lw[3]};
}

// conv_t(R) as MFMA GEMM: C[m=cell, uv=64] = Rpad[m,K=512] x W2T^T.
// t>=1: gate from partials first; resid = img - C via LDS-staged coalesced write.
// t<0: final fp32 reconstruction to outp.
__global__ __launch_bounds__(256) void kconvt(
    const ushort* __restrict__ rph, const ushort* __restrict__ rpl,
    const ushort* __restrict__ w2h, const ushort* __restrict__ w2l,
    const float* __restrict__ img, float* __restrict__ outp,
    ushort* __restrict__ rsh, ushort* __restrict__ rsl,
    const float* __restrict__ partials, int* __restrict__ flags, int t)
{
    const int tid = threadIdx.x;
    if (t >= 1) {   // convergence gate (deterministic, same in every block)
        __shared__ float red0[16];
        __shared__ int sgate;
        float d2 = 0.f, r2 = 0.f;
        for (int i = tid; i < NGRAD; i += 256) { d2 += partials[i]; r2 += partials[1024 + i]; }
        for (int off = 32; off; off >>= 1) { d2 += __shfl_down(d2, off, 64); r2 += __shfl_down(r2, off, 64); }
        int w = tid >> 6, l = tid & 63;
        if (l == 0) { red0[w] = d2; red0[8 + w] = r2; }
        __syncthreads();
        if (tid == 0) {
            float td = red0[0] + red0[1] + red0[2] + red0[3];
            float tr = red0[8] + red0[9] + red0[10] + red0[11];
            sgate = flags[t - 1] | ((td < 1e-4f * tr) ? 1 : 0);
            if (blockIdx.x == 0) flags[t] = sgate;
        }
        __syncthreads();
        if (sgate) return;
    }

    __shared__ uint4 lds[2048];   // Ahi[512] Alo[512] Bhi[512] Blo[512]
    const int bx = blockIdx.x;
    const int bid = ((bx & 7) << 6) | (bx >> 3);   // XCD swizzle, 512%8==0
    const int m0 = bid * 64;
    const int ml = tid >> 2, q = tid & 3;
    const int lane = tid & 63, wv = tid >> 6, wm = wv >> 1, wn = wv & 1, g = lane >> 5;
    const int mm = m0 + ml;
    const int b_ = mm >> 8, cell = mm & 255, px0 = cell >> 4, py0 = cell & 15;

    uint4 pa0, pa1, pb0, pb1, pc0, pc1, pd0, pd1;
    auto load_chunk = [&](int kc) {
        const int ij = kc >> 1, ic = ij >> 1, jc = ij & 1;
        const int nb = (kc & 1) * 64;
        const int off = ((b_ * CP + px0 + 1 - ic) * CP + py0 + 1 - jc) * NAT + nb + q * 16;
        pa0 = ((const uint4*)(rph + off))[0]; pa1 = ((const uint4*)(rph + off))[1];
        pb0 = ((const uint4*)(rpl + off))[0]; pb1 = ((const uint4*)(rpl + off))[1];
        const int bo = ml * 512 + kc * 64 + q * 16;
        pc0 = ((const uint4*)(w2h + bo))[0]; pc1 = ((const uint4*)(w2h + bo))[1];
        pd0 = ((const uint4*)(w2l + bo))[0]; pd1 = ((const uint4*)(w2l + bo))[1];
    };
    auto write_chunk = [&]() {
        int e0 = (q * 2) ^ (ml & 7), e1 = (q * 2 + 1) ^ (ml & 7);
        lds[       ml * 8 + e0] = pa0; lds[       ml * 8 + e1] = pa1;
        lds[512  + ml * 8 + e0] = pb0; lds[512  + ml * 8 + e1] = pb1;
        lds[1024 + ml * 8 + e0] = pc0; lds[1024 + ml * 8 + e1] = pc1;
        lds[1536 + ml * 8 + e0] = pd0; lds[1536 + ml * 8 + e1] = pd1;
    };

    f32x16 acc = {};
    const int arow = wm * 32 + (lane & 31);
    const int brow = wn * 32 + (lane & 31);
    const int ax = lane & 7;
    load_chunk(0); write_chunk(); __syncthreads();
    for (int kc = 0;; ++kc) {
        if (kc < 7) load_chunk(kc + 1);
#pragma unroll
        for (int ks = 0; ks < 4; ++ks) {
            int un = (ks * 2 + g) ^ ax;
            bf16x8 Ah = __builtin_bit_cast(bf16x8, lds[       arow * 8 + un]);
            bf16x8 Al = __builtin_bit_cast(bf16x8, lds[512  + arow * 8 + un]);
            bf16x8 Bh = __builtin_bit_cast(bf16x8, lds[1024 + brow * 8 + un]);
            bf16x8 Bl = __builtin_bit_cast(bf16x8, lds[1536 + brow * 8 + un]);
            acc = __builtin_amdgcn_mfma_f32_32x32x16_bf16(Ah, Bh, acc, 0, 0, 0);
            acc = __builtin_amdgcn_mfma_f32_32x32x16_bf16(Ah, Bl, acc, 0, 0, 0);
            acc = __builtin_amdgcn_mfma_f32_32x32x16_bf16(Al, Bh, acc, 0, 0, 0);
        }
        if (kc == 7) break;
        __syncthreads(); write_chunk(); __syncthreads();
    }

    // ---- epilogue: stage 32x128 image slab in LDS, write coalesced ----
    __syncthreads();                    // all fragment reads done
    float* ldsO = (float*)lds;          // [32][129] fp32 = 16.5 KB
    const int uvx = wn * 32 + (lane & 31);
    const int uu = uvx >> 3, vv = uvx & 7;
#pragma unroll
    for (int r = 0; r < 16; ++r) {
        int mr = m0 + wm * 32 + (r & 3) + 8 * (r >> 2) + 4 * g;
        int cl = mr & 255;
        int rowl = ((cl >> 4) & 3) * 8 + uu;
        int col = (cl & 15) * 8 + vv;
        ldsO[rowl * 129 + col] = acc[r];
    }
    __syncthreads();
    const int b0 = m0 >> 8;                  // batch
    const int x0 = ((m0 & 255) >> 4) * 8;    // first image row of slab
    const int row = tid >> 3, c0 = (tid & 7) * 16;
    const int base = b0 * DIM * DIM + (x0 + row) * DIM + c0;
    const float* lrow = &ldsO[row * 129 + c0];
    if (t >= 0) {
#pragma unroll
        for (int half = 0; half < 2; ++half) {
            uint hw[4], lw[4];
#pragma unroll
            for (int v = 0; v < 2; ++v) {
                int o = half * 8 + v * 4;
                float4 im = *(const float4*)&img[base + o];
                ushort h0,l0,h1,l1,h2,l2,h3,l3;
                split2(im.x - lrow[o + 0], h0, l0);
                split2(im.y - lrow[o + 1], h1, l1);
                split2(im.z - lrow[o + 2], h2, l2);
                split2(im.w - lrow[o + 3], h3, l3);
                hw[v*2+0] = pk(h0,h1); hw[v*2+1] = pk(h2,h3);
                lw[v*2+0] = pk(l0,l1); lw[v*2+1] = pk(l2,l3);
            }
            *(uint4*)&rsh[base + half * 8] = uint4{hw[0],hw[1],hw[2],hw[3]};
            *(uint4*)&rsl[base + half * 8] = uint4{lw[0],lw[1],lw[2],lw[3]};
        }
    } else {
#pragma unroll
        for (int v = 0; v < 4; ++v) {
            int o = v * 4;
            *(float4*)&outp[base + o] = float4{lrow[o], lrow[o+1], lrow[o+2], lrow[o+3]};
        }
    }
}

// grad MFMA GEMM g[m=64 cells, n=64 atoms] = residpatch[m,K=256] x WtT^T,
// fused SGD + soft-threshold + vectorized R(hi/lo) RMW + norm partials
__global__ __launch_bounds__(256) void kgrad(
    const ushort* __restrict__ rsh, const ushort* __restrict__ rsl,
    const ushort* __restrict__ wth, const ushort* __restrict__ wtl,
    ushort* __restrict__ rph, ushort* __restrict__ rpl,
    float* __restrict__ partials, const int* __restrict__ flags, int t)
{
    if (flags[t]) return;
    __shared__ uint4 lds[2048];   // 32 KB: Ahi[512] Alo[512] Bhi[512] Blo[512]
    __shared__ float red0[16];
    const int tid = threadIdx.x;
    const int bx = blockIdx.x;
    const int xcd = bx & 7;   // bijective XCD swizzle for nwg=450 (q=56,r=2)
    const int bid = (xcd < 2 ? xcd * 57 : 114 + (xcd - 2) * 56) + (bx >> 3);
    const int m0 = bid * 64;
    const int n0 = blockIdx.y * 64;
    const int ml = tid >> 2, q = tid & 3;
    const int lane = tid & 63, wv = tid >> 6, wm = wv >> 1, wn = wv & 1, g = lane >> 5;
    const int mm = m0 + ml;
    const int b_ = mm / 225, rem = mm % 225, px = rem / 15, py = rem % 15;

    uint4 pa0, pa1, pb0, pb1, pc0, pc1, pd0, pd1;
    auto load_chunk = [&](int kc) {
        const int off = b_ * DIM * DIM + (8 * px + kc * 4 + q) * DIM + 8 * py;
        pa0 = ((const uint4*)(rsh + off))[0]; pa1 = ((const uint4*)(rsh + off))[1];
        pb0 = ((const uint4*)(rsl + off))[0]; pb1 = ((const uint4*)(rsl + off))[1];
        const int bo = (n0 + ml) * 256 + kc * 64 + q * 16;
        pc0 = ((const uint4*)(wth + bo))[0]; pc1 = ((const uint4*)(wth + bo))[1];
        pd0 = ((const uint4*)(wtl + bo))[0]; pd1 = ((const uint4*)(wtl + bo))[1];
    };
    auto write_chunk = [&]() {
        int e0 = (q * 2) ^ (ml & 7), e1 = (q * 2 + 1) ^ (ml & 7);
        lds[       ml * 8 + e0] = pa0; lds[       ml * 8 + e1] = pa1;
        lds[512  + ml * 8 + e0] = pb0; lds[512  + ml * 8 + e1] = pb1;
        lds[1024 + ml * 8 + e0] = pc0; lds[1024 + ml * 8 + e1] = pc1;
        lds[1536 + ml * 8 + e0] = pd0; lds[1536 + ml * 8 + e1] = pd1;
    };

    f32x16 acc = {};
    const int arow = wm * 32 + (lane & 31);
    const int brow = wn * 32 + (lane & 31);
    const int ax = lane & 7;
    load_chunk(0); write_chunk(); __syncthreads();
    for (int kc = 0;; ++kc) {
        if (kc < 3) load_chunk(kc + 1);
#pragma unroll
        for (int ks = 0; ks < 4; ++ks) {
            int un = (ks * 2 + g) ^ ax;
            bf16x8 Ah = __builtin_bit_cast(bf16x8, lds[       arow * 8 + un]);
            bf16x8 Al = __builtin_bit_cast(bf16x8, lds[512  + arow * 8 + un]);
            bf16x8 Bh = __builtin_bit_cast(bf16x8, lds[1024 + brow * 8 + un]);
            bf16x8 Bl = __builtin_bit_cast(bf16x8, lds[1536 + brow * 8 + un]);
            acc = __builtin_amdgcn_mfma_f32_32x32x16_bf16(Ah, Bh, acc, 0, 0, 0);
            acc = __builtin_amdgcn_mfma_f32_32x32x16_bf16(Ah, Bl, acc, 0, 0, 0);
            acc = __builtin_amdgcn_mfma_f32_32x32x16_bf16(Al, Bh, acc, 0, 0, 0);
        }
        if (kc == 3) break;
        __syncthreads(); write_chunk(); __syncthreads();
    }

    // ---- stage acc -> ldsO[64][76] (stride 76 => <=2-way conflicts both phases)
    __syncthreads();
    float* ldsO = (float*)lds;
    {
        const int colL = wn * 32 + (lane & 31);
#pragma unroll
        for (int r = 0; r < 16; ++r) {
            int rowL = wm * 32 + (r & 3) + 8 * (r >> 2) + 4 * g;
            ldsO[rowL * 76 + colL] = acc[r];
        }
    }
    __syncthreads();

    // ---- vectorized RMW: 2 items/thread, 8 atoms (one uint4 per plane) each
    float d2 = 0.f, r2 = 0.f;
#pragma unroll
    for (int i = 0; i < 2; ++i) {
        int item = i * 256 + tid;
        int rowL = item >> 3, ch = item & 7;
        int mr = m0 + rowL;
        int bb = mr / 225, rm = mr % 225, pxx = rm / 15, pyy = rm % 15;
        int base = ((bb * CP + pxx + 1) * CP + pyy + 1) * NAT + n0 + ch * 8;
        uint4 hv = *(const uint4*)&rph[base];
        uint4 lv = *(const uint4*)&rpl[base];
        const float* lp = &ldsO[rowL * 76 + ch * 8];
        uint ho[4], lo_[4];
#pragma unroll
        for (int wd = 0; wd < 4; ++wd) {
            uint hw_ = ((const uint*)&hv)[wd], lw_ = ((const uint*)&lv)[wd];
            ushort nh0, nl0, nh1, nl1;
            {
                float rold = us2f((ushort)hw_) + us2f((ushort)lw_);
                float v = fmaf(STEP, lp[wd * 2 + 0], rold);
                float st = fmaxf(v - LMD, 0.f) - fmaxf(-v - LMD, 0.f);
                float df = st - rold;
                d2 += df * df; r2 += rold * rold;
                split2(st, nh0, nl0);
            }
            {
                float rold = us2f((ushort)(hw_ >> 16)) + us2f((ushort)(lw_ >> 16));
                float v = fmaf(STEP, lp[wd * 2 + 1], rold);
                float st = fmaxf(v - LMD, 0.f) - fmaxf(-v - LMD, 0.f);
                float df = st - rold;
                d2 += df * df; r2 += rold * rold;
                split2(st, nh1, nl1);
            }
            ho[wd] = pk(nh0, nh1); lo_[wd] = pk(nl0, nl1);
        }
        *(uint4*)&rph[base] = uint4{ho[0], ho[1], ho[2], ho[3]};
        *(uint4*)&rpl[base] = uint4{lo_[0], lo_[1], lo_[2], lo_[3]};
    }

    for (int off = 32; off; off >>= 1) { d2 += __shfl_down(d2, off, 64); r2 += __shfl_down(r2, off, 64); }
    int w = tid >> 6, l = tid & 63;
    if (l == 0) { red0[w] = d2; red0[8 + w] = r2; }
    __syncthreads();
    if (tid == 0) {
        float td = red0[0] + red0[1] + red0[2] + red0[3];
        float tr = red0[8] + red0[9] + red0[10] + red0[11];
        int pb2 = blockIdx.y * 450 + bid;
        partials[pb2] = td;
        partials[1024 + pb2] = tr;
    }
}

extern "C" void kernel_launch(void* const* d_in, const int* in_sizes, int n_in,
                              void* d_out, int out_size, void* d_ws, size_t ws_size,
                              hipStream_t stream) {
    const float* img = (const float*)d_in[0];
    const float* W   = (const float*)d_in[1];
    char* ws = (char*)d_ws;
    ushort* rph = (ushort*)(ws + O_RPH);
    ushort* rpl = (ushort*)(ws + O_RPL);
    ushort* rsh = (ushort*)(ws + O_RSH);
    ushort* rsl = (ushort*)(ws + O_RSL);
    ushort* w2h = (ushort*)(ws + O_W2H);
    ushort* w2l = (ushort*)(ws + O_W2L);
    ushort* wth = (ushort*)(ws + O_WTH);
    ushort* wtl = (ushort*)(ws + O_WTL);
    float* partials = (float*)(ws + O_PART);
    int*   flags    = (int*)(ws + O_FLAG);
    float* outp = (float*)d_out;

    kzero<<<4624, 256, 0, stream>>>((uint4*)(ws + O_RPH), flags);
    kprep<<<128, 256, 0, stream>>>(W, wth, wtl, w2h, w2l);
    kinit0<<<1024, 256, 0, stream>>>(img, rsh, rsl);            // t=0: resid = img
    kgrad<<<dim3(450, 2), 256, 0, stream>>>(rsh, rsl, wth, wtl, rph, rpl, partials, flags, 0);
    for (int t = 1; t < MAXIT; ++t) {
        kconvt<<<512, 256, 0, stream>>>(rph, rpl, w2h, w2l, img, nullptr, rsh, rsl, partials, flags, t);
        kgrad<<<dim3(450, 2), 256, 0, stream>>>(rsh, rsl, wth, wtl, rph, rpl, partials, flags, t);
    }
    kconvt<<<512, 256, 0, stream>>>(rph, rpl, w2h, w2l, img, outp, rsh, rsl, partials, flags, -1);
}

// Round 8
// 602.385 us; speedup vs baseline: 1.7408x; 1.0835x over previous
//
#include <hip/hip_runtime.h>
#include <stdint.h>

#define BATCH 128
#define NAT   128
#define DIM   128
#define CP    17
#define MAXIT 20
#define STEP  0.2f      // 2 * R_LR
#define LMD   0.005f
#define NGRAD 900

typedef short bf16x8 __attribute__((ext_vector_type(8)));   // 8 bf16 (4 VGPR)
typedef float f32x16 __attribute__((ext_vector_type(16)));  // 32x32 C/D

#define SZ_RP (BATCH*CP*CP*NAT)     // 4,734,976 elems
#define SZ_RS (BATCH*DIM*DIM)       // 2,097,152 elems
// workspace byte offsets (all 16B-aligned)
#define O_RPH  0
#define O_RPL  (O_RPH + SZ_RP*2)
#define O_RSH  (O_RPL + SZ_RP*2)
#define O_W2H  (O_RSH + SZ_RS*2)
#define O_W2L  (O_W2H + 64*512*2)
#define O_WTH  (O_W2L + 64*512*2)
#define O_WTL  (O_WTH + 128*256*2)
#define O_PART (O_WTL + 128*256*2)
#define O_FLAG (O_PART + 2048*4)

#define GLOAD16(gp, lp) __builtin_amdgcn_global_load_lds( \
    (const __attribute__((address_space(1))) uint32_t*)(gp), \
    (__attribute__((address_space(3))) uint32_t*)(lp), 16, 0, 0)

// split fp32 -> hi/lo bf16 (RNE); hi+lo carries ~16 mantissa bits
__device__ __forceinline__ void split2(float x, ushort& h, ushort& l) {
    uint32_t u = __float_as_uint(x);
    uint32_t hr = (u + 0x7FFFu + ((u >> 16) & 1u)) >> 16;
    h = (ushort)hr;
    float r = x - __uint_as_float(hr << 16);
    uint32_t u2 = __float_as_uint(r);
    l = (ushort)((u2 + 0x7FFFu + ((u2 >> 16) & 1u)) >> 16);
}
__device__ __forceinline__ float us2f(ushort u) {
    return __uint_as_float(((uint32_t)u) << 16);
}
__device__ __forceinline__ uint pk(ushort a, ushort b) {
    return (uint)a | ((uint)b << 16);
}
__device__ __forceinline__ ushort f2bf(float x) {   // RNE round to bf16
    uint32_t u = __float_as_uint(x);
    return (ushort)((u + 0x7FFFu + ((u >> 16) & 1u)) >> 16);
}

__global__ void kzero(uint4* __restrict__ rp, int* __restrict__ flags) {
    int i = blockIdx.x * 256 + threadIdx.x;
    rp[i] = uint4{0u, 0u, 0u, 0u};   // covers rpad hi+lo planes
    if (blockIdx.x == 0 && threadIdx.x < 32) flags[threadIdx.x] = 0;
}

// WtT = W layout [n][256]; W2T[uv][ij*128+n]; both as hi/lo bf16 planes
__global__ void kprep(const float* __restrict__ W,
                      ushort* __restrict__ wth, ushort* __restrict__ wtl,
                      ushort* __restrict__ w2h, ushort* __restrict__ w2l) {
    int tid = blockIdx.x * 256 + threadIdx.x;   // 32768
    int n = tid >> 8, kk = tid & 255;
    ushort h, l; split2(W[tid], h, l);
    wth[tid] = h; wtl[tid] = l;
    int kx = kk >> 4, ky = kk & 15;
    int uv = (kx & 7) * 8 + (ky & 7);
    int k2 = ((kx >> 3) * 2 + (ky >> 3)) * 128 + n;
    w2h[uv * 512 + k2] = h; w2l[uv * 512 + k2] = l;
}

// t=0 shortcut: R==0 -> resid = img (single bf16 plane)
__global__ void kinit0(const float* __restrict__ img, ushort* __restrict__ rsh) {
    int t8 = (blockIdx.x * 256 + threadIdx.x) * 8;
    uint hw[4];
#pragma unroll
    for (int v = 0; v < 2; ++v) {
        float4 im = *(const float4*)&img[t8 + v * 4];
        hw[v*2+0] = pk(f2bf(im.x), f2bf(im.y));
        hw[v*2+1] = pk(f2bf(im.z), f2bf(im.w));
    }
    *(uint4*)&rsh[t8] = uint4{hw[0],hw[1],hw[2],hw[3]};
}

// conv_t(R) as MFMA GEMM: C[m=cell, uv=64] = Rpad[m,K=512] x W2T^T.
// Staging: global_load_lds direct-to-LDS, double-buffered, 1 barrier/chunk.
// Each wave stages one plane (w0:Ah w1:Al w2:Bh w3:Bl); source pre-swizzled.
__global__ __launch_bounds__(256) void kconvt(
    const ushort* __restrict__ rph, const ushort* __restrict__ rpl,
    const ushort* __restrict__ w2h, const ushort* __restrict__ w2l,
    const float* __restrict__ img, float* __restrict__ outp,
    ushort* __restrict__ rsh,
    const float* __restrict__ partials, int* __restrict__ flags, int t)
{
    const int tid = threadIdx.x;
    if (t >= 1) {   // convergence gate (deterministic, same in every block)
        __shared__ float red0[16];
        __shared__ int sgate;
        float d2 = 0.f, r2 = 0.f;
        for (int i = tid; i < NGRAD; i += 256) { d2 += partials[i]; r2 += partials[1024 + i]; }
        for (int off = 32; off; off >>= 1) { d2 += __shfl_down(d2, off, 64); r2 += __shfl_down(r2, off, 64); }
        int w_ = tid >> 6, l = tid & 63;
        if (l == 0) { red0[w_] = d2; red0[8 + w_] = r2; }
        __syncthreads();
        if (tid == 0) {
            float td = red0[0] + red0[1] + red0[2] + red0[3];
            float tr = red0[8] + red0[9] + red0[10] + red0[11];
            sgate = flags[t - 1] | ((td < 1e-4f * tr) ? 1 : 0);
            if (blockIdx.x == 0) flags[t] = sgate;
        }
        __syncthreads();
        if (sgate) return;
    }

    __shared__ uint4 lds[4096];   // 2 bufs x {Ah,Al,Bh,Bl}[512] = 64 KB
    const int bx = blockIdx.x;
    const int bid = ((bx & 7) << 6) | (bx >> 3);   // XCD swizzle, 512%8==0
    const int m0 = bid * 64;
    const int lane = tid & 63, w = tid >> 6;
    const int wm = w >> 1, wn = w & 1, g = lane >> 5;

    // ---- staging precompute: wave w owns plane w; lane covers (ml, e=lane&7)
    const ushort* const srcs[4] = {rph, rpl, w2h, w2l};
    const ushort* src = srcs[w];
    const int u = (lane & 7) ^ ((lane >> 3) & 7);   // pre-swizzled source unit
    int off0[8];
#pragma unroll
    for (int i = 0; i < 8; ++i) {
        int ml = i * 8 + (lane >> 3);
        if (w < 2) {
            int mm = m0 + ml;
            int b_ = mm >> 8, cell = mm & 255, px0 = cell >> 4, py0 = cell & 15;
            off0[i] = ((b_ * CP + px0 + 1) * CP + py0 + 1) * NAT + u * 8;
        } else {
            off0[i] = ml * 512 + u * 8;
        }
    }
    auto stage = [&](int kc, int buf) {
        int delta;
        if (w < 2) {
            int ij = kc >> 1;
            delta = (kc & 1) * 64 - ((ij >> 1) * CP + (ij & 1)) * NAT;
        } else delta = kc * 64;
        uint4* base = lds + buf * 2048 + w * 512;   // wave-uniform LDS dest
#pragma unroll
        for (int i = 0; i < 8; ++i)
            GLOAD16(src + off0[i] + delta, base + i * 64);
    };

    f32x16 acc = {};
    const int arow = wm * 32 + (lane & 31);
    const int brow = wn * 32 + (lane & 31);
    const int ax = lane & 7;

    stage(0, 0);
    __syncthreads();                      // drains vmcnt -> chunk 0 resident
    for (int kc = 0;; ++kc) {
        const int cur = kc & 1;
        if (kc < 7) stage(kc + 1, cur ^ 1);
        const uint4* Lb = lds + cur * 2048;
#pragma unroll
        for (int ks = 0; ks < 4; ++ks) {
            int un = (ks * 2 + g) ^ ax;
            bf16x8 Ah = __builtin_bit_cast(bf16x8, Lb[       arow * 8 + un]);
            bf16x8 Al = __builtin_bit_cast(bf16x8, Lb[512  + arow * 8 + un]);
            bf16x8 Bh = __builtin_bit_cast(bf16x8, Lb[1024 + brow * 8 + un]);
            bf16x8 Bl = __builtin_bit_cast(bf16x8, Lb[1536 + brow * 8 + un]);
            acc = __builtin_amdgcn_mfma_f32_32x32x16_bf16(Ah, Bh, acc, 0, 0, 0);
            acc = __builtin_amdgcn_mfma_f32_32x32x16_bf16(Ah, Bl, acc, 0, 0, 0);
            acc = __builtin_amdgcn_mfma_f32_32x32x16_bf16(Al, Bh, acc, 0, 0, 0);
        }
        if (kc == 7) break;
        __syncthreads();                  // drains next-chunk loads + frees buf
    }

    // ---- epilogue: stage 32x128 image slab in LDS, write coalesced ----
    __syncthreads();
    float* ldsO = (float*)lds;            // [32][129] fp32, lives in buf0 region
    const int uvx = wn * 32 + (lane & 31);
    const int uu = uvx >> 3, vv = uvx & 7;
#pragma unroll
    for (int r = 0; r < 16; ++r) {
        int mr = m0 + wm * 32 + (r & 3) + 8 * (r >> 2) + 4 * g;
        int cl = mr & 255;
        ldsO[(((cl >> 4) & 3) * 8 + uu) * 129 + (cl & 15) * 8 + vv] = acc[r];
    }
    __syncthreads();
    const int b0 = m0 >> 8;
    const int x0 = ((m0 & 255) >> 4) * 8;
    const int row = tid >> 3, c0 = (tid & 7) * 16;
    const int base = b0 * DIM * DIM + (x0 + row) * DIM + c0;
    const float* lrow = &ldsO[row * 129 + c0];
    if (t >= 0) {
        uint hw[8];
#pragma unroll
        for (int v = 0; v < 4; ++v) {
            float4 im = *(const float4*)&img[base + v * 4];
            hw[v*2+0] = pk(f2bf(im.x - lrow[v*4+0]), f2bf(im.y - lrow[v*4+1]));
            hw[v*2+1] = pk(f2bf(im.z - lrow[v*4+2]), f2bf(im.w - lrow[v*4+3]));
        }
        *(uint4*)&rsh[base]     = uint4{hw[0],hw[1],hw[2],hw[3]};
        *(uint4*)&rsh[base + 8] = uint4{hw[4],hw[5],hw[6],hw[7]};
    } else {
#pragma unroll
        for (int v = 0; v < 4; ++v)
            *(float4*)&outp[base + v * 4] =
                float4{lrow[v*4], lrow[v*4+1], lrow[v*4+2], lrow[v*4+3]};
    }
}

// grad MFMA GEMM g[m=64 cells, n=64 atoms] = resid_bf16[m,K=256] x WtT^T,
// A single-plane (resid hi only): acc = Ah*Bh + Ah*Bl.
// Staging: gload_lds dbuf as kconvt (3 planes, 24 KB/chunk, 48 KB total).
__global__ __launch_bounds__(256) void kgrad(
    const ushort* __restrict__ rsh,
    const ushort* __restrict__ wth, const ushort* __restrict__ wtl,
    ushort* __restrict__ rph, ushort* __restrict__ rpl,
    float* __restrict__ partials, const int* __restrict__ flags, int t)
{
    if (flags[t]) return;
    __shared__ uint4 lds[3072];   // 2 bufs x {Ah,Bh,Bl}[512] = 48 KB
    __shared__ float red0[16];
    const int tid = threadIdx.x;
    const int bx = blockIdx.x;
    const int xcd = bx & 7;   // bijective XCD swizzle for nwg=450 (q=56,r=2)
    const int bid = (xcd < 2 ? xcd * 57 : 114 + (xcd - 2) * 56) + (bx >> 3);
    const int m0 = bid * 64;
    const int n0 = blockIdx.y * 64;
    const int lane = tid & 63, w = tid >> 6;
    const int wm = w >> 1, wn = w & 1, g = lane >> 5;

    // ---- staging precompute: 24 instrs, wave w gets j = w*6+i; plane = j>>3
    const ushort* const srcs[3] = {rsh, wth, wtl};
    const int u = (lane & 7) ^ ((lane >> 3) & 7);
    int off0[6]; const ushort* srcp[6];
#pragma unroll
    for (int i = 0; i < 6; ++i) {
        int j = w * 6 + i, p = j >> 3, jj = j & 7;
        int ml = jj * 8 + (lane >> 3);
        srcp[i] = srcs[p];
        if (p == 0) {
            int mA = m0 + ml, bA = mA / 225, rm = mA % 225, px = rm / 15, py = rm % 15;
            off0[i] = bA * DIM * DIM + (8 * px + (u >> 1)) * DIM + 8 * py + (u & 1) * 8;
        } else {
            off0[i] = (n0 + ml) * 256 + u * 8;
        }
    }
    auto stage = [&](int kc, int buf) {
#pragma unroll
        for (int i = 0; i < 6; ++i) {
            int j = w * 6 + i;
            int delta = (j < 8) ? kc * 512 : kc * 64;   // A: kc*4 rows; B: kc*64
            GLOAD16(srcp[i] + off0[i] + delta, lds + buf * 1536 + j * 64);
        }
    };

    f32x16 acc = {};
    const int arow = wm * 32 + (lane & 31);
    const int brow = wn * 32 + (lane & 31);
    const int ax = lane & 7;

    stage(0, 0);
    __syncthreads();
    for (int kc = 0;; ++kc) {
        const int cur = kc & 1;
        if (kc < 3) stage(kc + 1, cur ^ 1);
        const uint4* Lb = lds + cur * 1536;
#pragma unroll
        for (int ks = 0; ks < 4; ++ks) {
            int un = (ks * 2 + g) ^ ax;
            bf16x8 Ah = __builtin_bit_cast(bf16x8, Lb[       arow * 8 + un]);
            bf16x8 Bh = __builtin_bit_cast(bf16x8, Lb[512  + brow * 8 + un]);
            bf16x8 Bl = __builtin_bit_cast(bf16x8, Lb[1024 + brow * 8 + un]);
            acc = __builtin_amdgcn_mfma_f32_32x32x16_bf16(Ah, Bh, acc, 0, 0, 0);
            acc = __builtin_amdgcn_mfma_f32_32x32x16_bf16(Ah, Bl, acc, 0, 0, 0);
        }
        if (kc == 3) break;
        __syncthreads();
    }

    // ---- stage acc -> ldsO[64][76] (<=2-way conflicts both phases)
    __syncthreads();
    float* ldsO = (float*)lds;
    {
        const int colL = wn * 32 + (lane & 31);
#pragma unroll
        for (int r = 0; r < 16; ++r) {
            int rowL = wm * 32 + (r & 3) + 8 * (r >> 2) + 4 * g;
            ldsO[rowL * 76 + colL] = acc[r];
        }
    }
    __syncthreads();

    // ---- vectorized RMW: 2 items/thread, 8 atoms (one uint4 per plane) each
    float d2 = 0.f, r2 = 0.f;
#pragma unroll
    for (int i = 0; i < 2; ++i) {
        int item = i * 256 + tid;
        int rowL = item >> 3, ch = item & 7;
        int mr = m0 + rowL;
        int bb = mr / 225, rm = mr % 225, pxx = rm / 15, pyy = rm % 15;
        int base = ((bb * CP + pxx + 1) * CP + pyy + 1) * NAT + n0 + ch * 8;
        uint4 hv = *(const uint4*)&rph[base];
        uint4 lv = *(const uint4*)&rpl[base];
        const float* lp = &ldsO[rowL * 76 + ch * 8];
        uint ho[4], lo_[4];
#pragma unroll
        for (int wd = 0; wd < 4; ++wd) {
            uint hw_ = ((const uint*)&hv)[wd], lw_ = ((const uint*)&lv)[wd];
            ushort nh0, nl0, nh1, nl1;
            {
                float rold = us2f((ushort)hw_) + us2f((ushort)lw_);
                float v = fmaf(STEP, lp[wd * 2 + 0], rold);
                float st = fmaxf(v - LMD, 0.f) - fmaxf(-v - LMD, 0.f);
                float df = st - rold;
                d2 += df * df; r2 += rold * rold;
                split2(st, nh0, nl0);
            }
            {
                float rold = us2f((ushort)(hw_ >> 16)) + us2f((ushort)(lw_ >> 16));
                float v = fmaf(STEP, lp[wd * 2 + 1], rold);
                float st = fmaxf(v - LMD, 0.f) - fmaxf(-v - LMD, 0.f);
                float df = st - rold;
                d2 += df * df; r2 += rold * rold;
                split2(st, nh1, nl1);
            }
            ho[wd] = pk(nh0, nh1); lo_[wd] = pk(nl0, nl1);
        }
        *(uint4*)&rph[base] = uint4{ho[0], ho[1], ho[2], ho[3]};
        *(uint4*)&rpl[base] = uint4{lo_[0], lo_[1], lo_[2], lo_[3]};
    }

    for (int off = 32; off; off >>= 1) { d2 += __shfl_down(d2, off, 64); r2 += __shfl_down(r2, off, 64); }
    int w_ = tid >> 6, l = tid & 63;
    if (l == 0) { red0[w_] = d2; red0[8 + w_] = r2; }
    __syncthreads();
    if (tid == 0) {
        float td = red0[0] + red0[1] + red0[2] + red0[3];
        float tr = red0[8] + red0[9] + red0[10] + red0[11];
        int pb2 = blockIdx.y * 450 + bid;
        partials[pb2] = td;
        partials[1024 + pb2] = tr;
    }
}

extern "C" void kernel_launch(void* const* d_in, const int* in_sizes, int n_in,
                              void* d_out, int out_size, void* d_ws, size_t ws_size,
                              hipStream_t stream) {
    const float* img = (const float*)d_in[0];
    const float* W   = (const float*)d_in[1];
    char* ws = (char*)d_ws;
    ushort* rph = (ushort*)(ws + O_RPH);
    ushort* rpl = (ushort*)(ws + O_RPL);
    ushort* rsh = (ushort*)(ws + O_RSH);
    ushort* w2h = (ushort*)(ws + O_W2H);
    ushort* w2l = (ushort*)(ws + O_W2L);
    ushort* wth = (ushort*)(ws + O_WTH);
    ushort* wtl = (ushort*)(ws + O_WTL);
    float* partials = (float*)(ws + O_PART);
    int*   flags    = (int*)(ws + O_FLAG);
    float* outp = (float*)d_out;

    kzero<<<4624, 256, 0, stream>>>((uint4*)(ws + O_RPH), flags);
    kprep<<<128, 256, 0, stream>>>(W, wth, wtl, w2h, w2l);
    kinit0<<<1024, 256, 0, stream>>>(img, rsh);                 // t=0: resid = img
    kgrad<<<dim3(450, 2), 256, 0, stream>>>(rsh, wth, wtl, rph, rpl, partials, flags, 0);
    for (int t = 1; t < MAXIT; ++t) {
        kconvt<<<512, 256, 0, stream>>>(rph, rpl, w2h, w2l, img, nullptr, rsh, partials, flags, t);
        kgrad<<<dim3(450, 2), 256, 0, stream>>>(rsh, wth, wtl, rph, rpl, partials, flags, t);
    }
    kconvt<<<512, 256, 0, stream>>>(rph, rpl, w2h, w2l, img, outp, rsh, partials, flags, -1);
}

// Round 9
// 473.498 us; speedup vs baseline: 2.2146x; 1.2722x over previous
//
#include <hip/hip_runtime.h>
#include <stdint.h>

#define BATCH 128
#define NAT   128
#define DIM   128
#define CP    17
#define MAXIT 20
#define STEP  0.2f      // 2 * R_LR
#define LMD   0.005f
#define NGRAD 900

typedef short bf16x8 __attribute__((ext_vector_type(8)));   // 8 bf16 (4 VGPR)
typedef float f32x16 __attribute__((ext_vector_type(16)));  // 32x32 C/D

#define SZ_RP (BATCH*CP*CP*NAT)     // 4,734,976 elems
#define SZ_RS (BATCH*DIM*DIM)       // 2,097,152 elems
// workspace byte offsets (all 16B-aligned)
#define O_RPH  0
#define O_RPL  (O_RPH + SZ_RP*2)
#define O_RSH  (O_RPL + SZ_RP*2)
#define O_W2H  (O_RSH + SZ_RS*2)
#define O_W2L  (O_W2H + 64*512*2)
#define O_WTH  (O_W2L + 64*512*2)
#define O_WTL  (O_WTH + 128*256*2)
#define O_PART (O_WTL + 128*256*2)
#define O_FLAG (O_PART + 2048*4)

#define GLOAD16(gp, lp) __builtin_amdgcn_global_load_lds( \
    (const __attribute__((address_space(1))) uint32_t*)(gp), \
    (__attribute__((address_space(3))) uint32_t*)(lp), 16, 0, 0)

// split fp32 -> hi/lo bf16 (RNE); hi+lo carries ~16 mantissa bits
__device__ __forceinline__ void split2(float x, ushort& h, ushort& l) {
    uint32_t u = __float_as_uint(x);
    uint32_t hr = (u + 0x7FFFu + ((u >> 16) & 1u)) >> 16;
    h = (ushort)hr;
    float r = x - __uint_as_float(hr << 16);
    uint32_t u2 = __float_as_uint(r);
    l = (ushort)((u2 + 0x7FFFu + ((u2 >> 16) & 1u)) >> 16);
}
__device__ __forceinline__ float us2f(ushort u) {
    return __uint_as_float(((uint32_t)u) << 16);
}
__device__ __forceinline__ uint pk(ushort a, ushort b) {
    return (uint)a | ((uint)b << 16);
}
__device__ __forceinline__ ushort f2bf(float x) {   // RNE round to bf16
    uint32_t u = __float_as_uint(x);
    return (ushort)((u + 0x7FFFu + ((u >> 16) & 1u)) >> 16);
}

__global__ void kzero(uint4* __restrict__ rp, int* __restrict__ flags) {
    int i = blockIdx.x * 256 + threadIdx.x;
    rp[i] = uint4{0u, 0u, 0u, 0u};   // covers rpad hi+lo planes
    if (blockIdx.x == 0 && threadIdx.x < 32) flags[threadIdx.x] = 0;
}

// WtT = W layout [n][256]; W2T[uv][ij*128+n]; both as hi/lo bf16 planes
__global__ void kprep(const float* __restrict__ W,
                      ushort* __restrict__ wth, ushort* __restrict__ wtl,
                      ushort* __restrict__ w2h, ushort* __restrict__ w2l) {
    int tid = blockIdx.x * 256 + threadIdx.x;   // 32768
    int n = tid >> 8, kk = tid & 255;
    ushort h, l; split2(W[tid], h, l);
    wth[tid] = h; wtl[tid] = l;
    int kx = kk >> 4, ky = kk & 15;
    int uv = (kx & 7) * 8 + (ky & 7);
    int k2 = ((kx >> 3) * 2 + (ky >> 3)) * 128 + n;
    w2h[uv * 512 + k2] = h; w2l[uv * 512 + k2] = l;
}

// t=0 shortcut: R==0 -> resid = img (single bf16 plane)
__global__ void kinit0(const float* __restrict__ img, ushort* __restrict__ rsh) {
    int t8 = (blockIdx.x * 256 + threadIdx.x) * 8;
    uint hw[4];
#pragma unroll
    for (int v = 0; v < 2; ++v) {
        float4 im = *(const float4*)&img[t8 + v * 4];
        hw[v*2+0] = pk(f2bf(im.x), f2bf(im.y));
        hw[v*2+1] = pk(f2bf(im.z), f2bf(im.w));
    }
    *(uint4*)&rsh[t8] = uint4{hw[0],hw[1],hw[2],hw[3]};
}

// resid kconvt: pure-bf16 GEMM C[m=cell,uv] = Rhi[m,512] x W2hi^T.
// Depth-3 prefetch: 4 LDS bufs, counted vmcnt, raw barriers.
__global__ __launch_bounds__(256) void kconvt(
    const ushort* __restrict__ rph, const ushort* __restrict__ w2h,
    const float* __restrict__ img, ushort* __restrict__ rsh,
    const float* __restrict__ partials, int* __restrict__ flags, int t)
{
    const int tid = threadIdx.x;
    {   // convergence gate (deterministic, same in every block)
        __shared__ float red0[16];
        __shared__ int sgate;
        float d2 = 0.f, r2 = 0.f;
        for (int i = tid; i < NGRAD; i += 256) { d2 += partials[i]; r2 += partials[1024 + i]; }
        for (int off = 32; off; off >>= 1) { d2 += __shfl_down(d2, off, 64); r2 += __shfl_down(r2, off, 64); }
        int w_ = tid >> 6, l = tid & 63;
        if (l == 0) { red0[w_] = d2; red0[8 + w_] = r2; }
        __syncthreads();
        if (tid == 0) {
            float td = red0[0] + red0[1] + red0[2] + red0[3];
            float tr = red0[8] + red0[9] + red0[10] + red0[11];
            sgate = flags[t - 1] | ((td < 1e-4f * tr) ? 1 : 0);
            if (blockIdx.x == 0) flags[t] = sgate;
        }
        __syncthreads();
        if (sgate) return;
    }

    __shared__ uint4 lds[4096];   // 4 bufs x {Ah[512],Bh[512]} = 64 KB
    const int bx = blockIdx.x;
    const int bid = ((bx & 7) << 6) | (bx >> 3);   // XCD swizzle, 512%8==0
    const int m0 = bid * 64;
    const int lane = tid & 63, w = tid >> 6;
    const int wm = w >> 1, wn = w & 1, g = lane >> 5;
    const int u = (lane & 7) ^ ((lane >> 3) & 7);   // pre-swizzled source unit

    // 16 slots: s<8 A-plane rows, s>=8 B-plane rows; wave w owns s=w*4..+3
    int off0[4]; const ushort* srcp[4];
#pragma unroll
    for (int i = 0; i < 4; ++i) {
        int s = w * 4 + i;
        if (s < 8) {
            int ml = s * 8 + (lane >> 3);
            int mm = m0 + ml;
            int b_ = mm >> 8, cell = mm & 255, px0 = cell >> 4, py0 = cell & 15;
            off0[i] = ((b_ * CP + px0 + 1) * CP + py0 + 1) * NAT + u * 8;
            srcp[i] = rph;
        } else {
            int ml = (s - 8) * 8 + (lane >> 3);
            off0[i] = ml * 512 + u * 8;
            srcp[i] = w2h;
        }
    }
    auto stage = [&](int kc, int buf) {
        int ij = kc >> 1;
        int dA = (kc & 1) * 64 - ((ij >> 1) * CP + (ij & 1)) * NAT;
        int dB = kc * 64;
        uint4* base = lds + buf * 1024;
#pragma unroll
        for (int i = 0; i < 4; ++i) {
            int s = w * 4 + i;
            GLOAD16(srcp[i] + off0[i] + (s < 8 ? dA : dB), base + s * 64);
        }
    };

    f32x16 acc = {};
    const int arow = wm * 32 + (lane & 31);
    const int brow = wn * 32 + (lane & 31);
    const int ax = lane & 7;     // = arow&7 = brow&7

    stage(0, 0); stage(1, 1); stage(2, 2);
    for (int kc = 0; kc < 8; ++kc) {
        if (kc < 5) stage(kc + 3, (kc + 3) & 3);
        int nf = 7 - kc; nf = nf > 3 ? 3 : nf;    // chunks in flight past kc
        switch (nf) {
            case 3: asm volatile("s_waitcnt vmcnt(12)" ::: "memory"); break;
            case 2: asm volatile("s_waitcnt vmcnt(8)"  ::: "memory"); break;
            case 1: asm volatile("s_waitcnt vmcnt(4)"  ::: "memory"); break;
            default: asm volatile("s_waitcnt vmcnt(0)" ::: "memory"); break;
        }
        __builtin_amdgcn_s_barrier();            // chunk kc resident for all waves
        __builtin_amdgcn_sched_barrier(0);
        const uint4* Lb = lds + (kc & 3) * 1024;
#pragma unroll
        for (int ks = 0; ks < 4; ++ks) {
            int un = (ks * 2 + g) ^ ax;
            bf16x8 Ah = __builtin_bit_cast(bf16x8, Lb[      arow * 8 + un]);
            bf16x8 Bh = __builtin_bit_cast(bf16x8, Lb[512 + brow * 8 + un]);
            acc = __builtin_amdgcn_mfma_f32_32x32x16_bf16(Ah, Bh, acc, 0, 0, 0);
        }
        __builtin_amdgcn_sched_barrier(0);
        __builtin_amdgcn_s_barrier();            // buf free for overwrite
    }

    // ---- epilogue: stage 32x128 image slab in LDS, write resid coalesced ----
    float* ldsO = (float*)lds;            // [32][129] fp32
    const int uvx = wn * 32 + (lane & 31);
    const int uu = uvx >> 3, vv = uvx & 7;
#pragma unroll
    for (int r = 0; r < 16; ++r) {
        int mr = m0 + wm * 32 + (r & 3) + 8 * (r >> 2) + 4 * g;
        int cl = mr & 255;
        ldsO[(((cl >> 4) & 3) * 8 + uu) * 129 + (cl & 15) * 8 + vv] = acc[r];
    }
    __syncthreads();
    const int b0 = m0 >> 8;
    const int x0 = ((m0 & 255) >> 4) * 8;
    const int row = tid >> 3, c0 = (tid & 7) * 16;
    const int base = b0 * DIM * DIM + (x0 + row) * DIM + c0;
    const float* lrow = &ldsO[row * 129 + c0];
    uint hw[8];
#pragma unroll
    for (int v = 0; v < 4; ++v) {
        float4 im = *(const float4*)&img[base + v * 4];
        hw[v*2+0] = pk(f2bf(im.x - lrow[v*4+0]), f2bf(im.y - lrow[v*4+1]));
        hw[v*2+1] = pk(f2bf(im.z - lrow[v*4+2]), f2bf(im.w - lrow[v*4+3]));
    }
    *(uint4*)&rsh[base]     = uint4{hw[0],hw[1],hw[2],hw[3]};
    *(uint4*)&rsh[base + 8] = uint4{hw[4],hw[5],hw[6],hw[7]};
}

// grad: pure-bf16 GEMM g[m=64 cells, n=64 atoms] = resid[m,256] x Wthi^T.
// Depth-2 prefetch: 3 LDS bufs, counted vmcnt, raw barriers.
__global__ __launch_bounds__(256) void kgrad(
    const ushort* __restrict__ rsh, const ushort* __restrict__ wth,
    ushort* __restrict__ rph, ushort* __restrict__ rpl,
    float* __restrict__ partials, const int* __restrict__ flags, int t)
{
    if (flags[t]) return;
    __shared__ uint4 lds[3072];   // 3 bufs x {A[512],B[512]} = 48 KB
    __shared__ float red0[16];
    const int tid = threadIdx.x;
    const int bx = blockIdx.x;
    const int xcd = bx & 7;   // bijective XCD swizzle for nwg=450 (q=56,r=2)
    const int bid = (xcd < 2 ? xcd * 57 : 114 + (xcd - 2) * 56) + (bx >> 3);
    const int m0 = bid * 64;
    const int n0 = blockIdx.y * 64;
    const int lane = tid & 63, w = tid >> 6;
    const int wm = w >> 1, wn = w & 1, g = lane >> 5;
    const int u = (lane & 7) ^ ((lane >> 3) & 7);

    int off0[4]; const ushort* srcp[4];
#pragma unroll
    for (int i = 0; i < 4; ++i) {
        int s = w * 4 + i;
        if (s < 8) {
            int ml = s * 8 + (lane >> 3);
            int mA = m0 + ml, bA = mA / 225, rm = mA % 225, px = rm / 15, py = rm % 15;
            off0[i] = bA * DIM * DIM + (8 * px + (u >> 1)) * DIM + 8 * py + (u & 1) * 8;
            srcp[i] = rsh;
        } else {
            int ml = (s - 8) * 8 + (lane >> 3);
            off0[i] = (n0 + ml) * 256 + u * 8;
            srcp[i] = wth;
        }
    }
    auto stage = [&](int kc, int buf) {
        uint4* base = lds + buf * 1024;
#pragma unroll
        for (int i = 0; i < 4; ++i) {
            int s = w * 4 + i;
            GLOAD16(srcp[i] + off0[i] + (s < 8 ? kc * 512 : kc * 64), base + s * 64);
        }
    };

    f32x16 acc = {};
    const int arow = wm * 32 + (lane & 31);
    const int brow = wn * 32 + (lane & 31);
    const int ax = lane & 7;

    stage(0, 0); stage(1, 1);
    for (int kc = 0; kc < 4; ++kc) {
        if (kc < 2) stage(kc + 2, (kc + 2) % 3);
        int nf = 3 - kc; nf = nf > 2 ? 2 : nf;
        switch (nf) {
            case 2: asm volatile("s_waitcnt vmcnt(8)" ::: "memory"); break;
            case 1: asm volatile("s_waitcnt vmcnt(4)" ::: "memory"); break;
            default: asm volatile("s_waitcnt vmcnt(0)" ::: "memory"); break;
        }
        __builtin_amdgcn_s_barrier();
        __builtin_amdgcn_sched_barrier(0);
        const uint4* Lb = lds + (kc % 3) * 1024;
#pragma unroll
        for (int ks = 0; ks < 4; ++ks) {
            int un = (ks * 2 + g) ^ ax;
            bf16x8 Ah = __builtin_bit_cast(bf16x8, Lb[      arow * 8 + un]);
            bf16x8 Bh = __builtin_bit_cast(bf16x8, Lb[512 + brow * 8 + un]);
            acc = __builtin_amdgcn_mfma_f32_32x32x16_bf16(Ah, Bh, acc, 0, 0, 0);
        }
        __builtin_amdgcn_sched_barrier(0);
        __builtin_amdgcn_s_barrier();
    }

    // ---- stage acc -> ldsO[64][76] (<=2-way conflicts both phases)
    float* ldsO = (float*)lds;
    {
        const int colL = wn * 32 + (lane & 31);
#pragma unroll
        for (int r = 0; r < 16; ++r) {
            int rowL = wm * 32 + (r & 3) + 8 * (r >> 2) + 4 * g;
            ldsO[rowL * 76 + colL] = acc[r];
        }
    }
    __syncthreads();

    // ---- vectorized RMW: 2 items/thread, 8 atoms (one uint4 per plane) each
    float d2 = 0.f, r2 = 0.f;
#pragma unroll
    for (int i = 0; i < 2; ++i) {
        int item = i * 256 + tid;
        int rowL = item >> 3, ch = item & 7;
        int mr = m0 + rowL;
        int bb = mr / 225, rm = mr % 225, pxx = rm / 15, pyy = rm % 15;
        int base = ((bb * CP + pxx + 1) * CP + pyy + 1) * NAT + n0 + ch * 8;
        uint4 hv = *(const uint4*)&rph[base];
        uint4 lv = *(const uint4*)&rpl[base];
        const float* lp = &ldsO[rowL * 76 + ch * 8];
        uint ho[4], lo_[4];
#pragma unroll
        for (int wd = 0; wd < 4; ++wd) {
            uint hw_ = ((const uint*)&hv)[wd], lw_ = ((const uint*)&lv)[wd];
            ushort nh0, nl0, nh1, nl1;
            {
                float rold = us2f((ushort)hw_) + us2f((ushort)lw_);
                float v = fmaf(STEP, lp[wd * 2 + 0], rold);
                float st = fmaxf(v - LMD, 0.f) - fmaxf(-v - LMD, 0.f);
                float df = st - rold;
                d2 += df * df; r2 += rold * rold;
                split2(st, nh0, nl0);
            }
            {
                float rold = us2f((ushort)(hw_ >> 16)) + us2f((ushort)(lw_ >> 16));
                float v = fmaf(STEP, lp[wd * 2 + 1], rold);
                float st = fmaxf(v - LMD, 0.f) - fmaxf(-v - LMD, 0.f);
                float df = st - rold;
                d2 += df * df; r2 += rold * rold;
                split2(st, nh1, nl1);
            }
            ho[wd] = pk(nh0, nh1); lo_[wd] = pk(nl0, nl1);
        }
        *(uint4*)&rph[base] = uint4{ho[0], ho[1], ho[2], ho[3]};
        *(uint4*)&rpl[base] = uint4{lo_[0], lo_[1], lo_[2], lo_[3]};
    }

    for (int off = 32; off; off >>= 1) { d2 += __shfl_down(d2, off, 64); r2 += __shfl_down(r2, off, 64); }
    int w_ = tid >> 6, l = tid & 63;
    if (l == 0) { red0[w_] = d2; red0[8 + w_] = r2; }
    __syncthreads();
    if (tid == 0) {
        float td = red0[0] + red0[1] + red0[2] + red0[3];
        float tr = red0[8] + red0[9] + red0[10] + red0[11];
        int pb2 = blockIdx.y * 450 + bid;
        partials[pb2] = td;
        partials[1024 + pb2] = tr;
    }
}

// final reconstruction: full 3-term Markidis from R hi/lo (round-8 structure)
__global__ __launch_bounds__(256) void kfinal(
    const ushort* __restrict__ rph, const ushort* __restrict__ rpl,
    const ushort* __restrict__ w2h, const ushort* __restrict__ w2l,
    float* __restrict__ outp)
{
    const int tid = threadIdx.x;
    __shared__ uint4 lds[4096];   // 2 bufs x {Ah,Al,Bh,Bl}[512] = 64 KB
    const int bx = blockIdx.x;
    const int bid = ((bx & 7) << 6) | (bx >> 3);
    const int m0 = bid * 64;
    const int lane = tid & 63, w = tid >> 6;
    const int wm = w >> 1, wn = w & 1, g = lane >> 5;

    const ushort* const srcs[4] = {rph, rpl, w2h, w2l};
    const ushort* src = srcs[w];
    const int u = (lane & 7) ^ ((lane >> 3) & 7);
    int off0[8];
#pragma unroll
    for (int i = 0; i < 8; ++i) {
        int ml = i * 8 + (lane >> 3);
        if (w < 2) {
            int mm = m0 + ml;
            int b_ = mm >> 8, cell = mm & 255, px0 = cell >> 4, py0 = cell & 15;
            off0[i] = ((b_ * CP + px0 + 1) * CP + py0 + 1) * NAT + u * 8;
        } else {
            off0[i] = ml * 512 + u * 8;
        }
    }
    auto stage = [&](int kc, int buf) {
        int delta;
        if (w < 2) {
            int ij = kc >> 1;
            delta = (kc & 1) * 64 - ((ij >> 1) * CP + (ij & 1)) * NAT;
        } else delta = kc * 64;
        uint4* base = lds + buf * 2048 + w * 512;
#pragma unroll
        for (int i = 0; i < 8; ++i)
            GLOAD16(src + off0[i] + delta, base + i * 64);
    };

    f32x16 acc = {};
    const int arow = wm * 32 + (lane & 31);
    const int brow = wn * 32 + (lane & 31);
    const int ax = lane & 7;

    stage(0, 0);
    __syncthreads();
    for (int kc = 0;; ++kc) {
        const int cur = kc & 1;
        if (kc < 7) stage(kc + 1, cur ^ 1);
        const uint4* Lb = lds + cur * 2048;
#pragma unroll
        for (int ks = 0; ks < 4; ++ks) {
            int un = (ks * 2 + g) ^ ax;
            bf16x8 Ah = __builtin_bit_cast(bf16x8, Lb[       arow * 8 + un]);
            bf16x8 Al = __builtin_bit_cast(bf16x8, Lb[512  + arow * 8 + un]);
            bf16x8 Bh = __builtin_bit_cast(bf16x8, Lb[1024 + brow * 8 + un]);
            bf16x8 Bl = __builtin_bit_cast(bf16x8, Lb[1536 + brow * 8 + un]);
            acc = __builtin_amdgcn_mfma_f32_32x32x16_bf16(Ah, Bh, acc, 0, 0, 0);
            acc = __builtin_amdgcn_mfma_f32_32x32x16_bf16(Ah, Bl, acc, 0, 0, 0);
            acc = __builtin_amdgcn_mfma_f32_32x32x16_bf16(Al, Bh, acc, 0, 0, 0);
        }
        if (kc == 7) break;
        __syncthreads();
    }

    __syncthreads();
    float* ldsO = (float*)lds;
    const int uvx = wn * 32 + (lane & 31);
    const int uu = uvx >> 3, vv = uvx & 7;
#pragma unroll
    for (int r = 0; r < 16; ++r) {
        int mr = m0 + wm * 32 + (r & 3) + 8 * (r >> 2) + 4 * g;
        int cl = mr & 255;
        ldsO[(((cl >> 4) & 3) * 8 + uu) * 129 + (cl & 15) * 8 + vv] = acc[r];
    }
    __syncthreads();
    const int b0 = m0 >> 8;
    const int x0 = ((m0 & 255) >> 4) * 8;
    const int row = tid >> 3, c0 = (tid & 7) * 16;
    const int base = b0 * DIM * DIM + (x0 + row) * DIM + c0;
    const float* lrow = &ldsO[row * 129 + c0];
#pragma unroll
    for (int v = 0; v < 4; ++v)
        *(float4*)&outp[base + v * 4] =
            float4{lrow[v*4], lrow[v*4+1], lrow[v*4+2], lrow[v*4+3]};
}

extern "C" void kernel_launch(void* const* d_in, const int* in_sizes, int n_in,
                              void* d_out, int out_size, void* d_ws, size_t ws_size,
                              hipStream_t stream) {
    const float* img = (const float*)d_in[0];
    const float* W   = (const float*)d_in[1];
    char* ws = (char*)d_ws;
    ushort* rph = (ushort*)(ws + O_RPH);
    ushort* rpl = (ushort*)(ws + O_RPL);
    ushort* rsh = (ushort*)(ws + O_RSH);
    ushort* w2h = (ushort*)(ws + O_W2H);
    ushort* w2l = (ushort*)(ws + O_W2L);
    ushort* wth = (ushort*)(ws + O_WTH);
    ushort* wtl = (ushort*)(ws + O_WTL);
    float* partials = (float*)(ws + O_PART);
    int*   flags    = (int*)(ws + O_FLAG);
    float* outp = (float*)d_out;

    kzero<<<4624, 256, 0, stream>>>((uint4*)(ws + O_RPH), flags);
    kprep<<<128, 256, 0, stream>>>(W, wth, wtl, w2h, w2l);
    kinit0<<<1024, 256, 0, stream>>>(img, rsh);                 // t=0: resid = img
    kgrad<<<dim3(450, 2), 256, 0, stream>>>(rsh, wth, rph, rpl, partials, flags, 0);
    for (int t = 1; t < MAXIT; ++t) {
        kconvt<<<512, 256, 0, stream>>>(rph, w2h, img, rsh, partials, flags, t);
        kgrad<<<dim3(450, 2), 256, 0, stream>>>(rsh, wth, rph, rpl, partials, flags, t);
    }
    kfinal<<<512, 256, 0, stream>>>(rph, rpl, w2h, w2l, outp);
}

// Round 10
// 452.657 us; speedup vs baseline: 2.3166x; 1.0460x over previous
//
#include <hip/hip_runtime.h>
#include <stdint.h>

#define BATCH 128
#define NAT   128
#define DIM   128
#define CP    17
#define MAXIT 20
#define STEP  0.2f      // 2 * R_LR
#define LMD   0.005f
#define NGRAD 900

typedef short bf16x8 __attribute__((ext_vector_type(8)));   // 8 bf16 (4 VGPR)
typedef float f32x16 __attribute__((ext_vector_type(16)));  // 32x32 C/D

#define SZ_RP (BATCH*CP*CP*NAT)     // 4,734,976 elems
#define SZ_RS (BATCH*DIM*DIM)       // 2,097,152 elems
// workspace byte offsets (all 16B-aligned). R = single bf16 plane now.
#define O_RP   0
#define O_RSH  (O_RP + SZ_RP*2)
#define O_W2H  (O_RSH + SZ_RS*2)
#define O_W2L  (O_W2H + 64*512*2)
#define O_WTH  (O_W2L + 64*512*2)
#define O_WTL  (O_WTH + 128*256*2)
#define O_PART (O_WTL + 128*256*2)
#define O_FLAG (O_PART + 2048*4)

#define GLOAD16(gp, lp) __builtin_amdgcn_global_load_lds( \
    (const __attribute__((address_space(1))) uint32_t*)(gp), \
    (__attribute__((address_space(3))) uint32_t*)(lp), 16, 0, 0)

// split fp32 -> hi/lo bf16 (RNE)
__device__ __forceinline__ void split2(float x, ushort& h, ushort& l) {
    uint32_t u = __float_as_uint(x);
    uint32_t hr = (u + 0x7FFFu + ((u >> 16) & 1u)) >> 16;
    h = (ushort)hr;
    float r = x - __uint_as_float(hr << 16);
    uint32_t u2 = __float_as_uint(r);
    l = (ushort)((u2 + 0x7FFFu + ((u2 >> 16) & 1u)) >> 16);
}
__device__ __forceinline__ float us2f(ushort u) {
    return __uint_as_float(((uint32_t)u) << 16);
}
__device__ __forceinline__ uint pk(ushort a, ushort b) {
    return (uint)a | ((uint)b << 16);
}
__device__ __forceinline__ ushort f2bf(float x) {   // RNE round to bf16
    uint32_t u = __float_as_uint(x);
    return (ushort)((u + 0x7FFFu + ((u >> 16) & 1u)) >> 16);
}

__global__ void kzero(uint4* __restrict__ rp, int* __restrict__ flags) {
    int i = blockIdx.x * 256 + threadIdx.x;
    rp[i] = uint4{0u, 0u, 0u, 0u};   // R single plane
    if (blockIdx.x == 0 && threadIdx.x < 32) flags[threadIdx.x] = 0;
}

// WtT = W layout [n][256]; W2T[uv][ij*128+n]; both as hi/lo bf16 planes
__global__ void kprep(const float* __restrict__ W,
                      ushort* __restrict__ wth, ushort* __restrict__ wtl,
                      ushort* __restrict__ w2h, ushort* __restrict__ w2l) {
    int tid = blockIdx.x * 256 + threadIdx.x;   // 32768
    int n = tid >> 8, kk = tid & 255;
    ushort h, l; split2(W[tid], h, l);
    wth[tid] = h; wtl[tid] = l;
    int kx = kk >> 4, ky = kk & 15;
    int uv = (kx & 7) * 8 + (ky & 7);
    int k2 = ((kx >> 3) * 2 + (ky >> 3)) * 128 + n;
    w2h[uv * 512 + k2] = h; w2l[uv * 512 + k2] = l;
}

// t=0 shortcut: R==0 -> resid = img (single bf16 plane)
__global__ void kinit0(const float* __restrict__ img, ushort* __restrict__ rsh) {
    int t8 = (blockIdx.x * 256 + threadIdx.x) * 8;
    uint hw[4];
#pragma unroll
    for (int v = 0; v < 2; ++v) {
        float4 im = *(const float4*)&img[t8 + v * 4];
        hw[v*2+0] = pk(f2bf(im.x), f2bf(im.y));
        hw[v*2+1] = pk(f2bf(im.z), f2bf(im.w));
    }
    *(uint4*)&rsh[t8] = uint4{hw[0],hw[1],hw[2],hw[3]};
}

// resid kconvt: pure-bf16 GEMM C[m=cell,uv] = R[m,512] x W2hi^T.
// Depth-3 prefetch: 4 LDS bufs, counted vmcnt, raw barriers.
__global__ __launch_bounds__(256) void kconvt(
    const ushort* __restrict__ rp, const ushort* __restrict__ w2h,
    const float* __restrict__ img, ushort* __restrict__ rsh,
    const float* __restrict__ partials, int* __restrict__ flags, int t)
{
    const int tid = threadIdx.x;
    {   // convergence gate (deterministic, same in every block)
        __shared__ float red0[16];
        __shared__ int sgate;
        float d2 = 0.f, r2 = 0.f;
        for (int i = tid; i < NGRAD; i += 256) { d2 += partials[i]; r2 += partials[1024 + i]; }
        for (int off = 32; off; off >>= 1) { d2 += __shfl_down(d2, off, 64); r2 += __shfl_down(r2, off, 64); }
        int w_ = tid >> 6, l = tid & 63;
        if (l == 0) { red0[w_] = d2; red0[8 + w_] = r2; }
        __syncthreads();
        if (tid == 0) {
            float td = red0[0] + red0[1] + red0[2] + red0[3];
            float tr = red0[8] + red0[9] + red0[10] + red0[11];
            sgate = flags[t - 1] | ((td < 1e-4f * tr) ? 1 : 0);
            if (blockIdx.x == 0) flags[t] = sgate;
        }
        __syncthreads();
        if (sgate) return;
    }

    __shared__ uint4 lds[4096];   // 4 bufs x {A[512],B[512]} = 64 KB
    const int bx = blockIdx.x;
    const int bid = ((bx & 7) << 6) | (bx >> 3);   // XCD swizzle, 512%8==0
    const int m0 = bid * 64;
    const int lane = tid & 63, w = tid >> 6;
    const int wm = w >> 1, wn = w & 1, g = lane >> 5;
    const int u = (lane & 7) ^ ((lane >> 3) & 7);   // pre-swizzled source unit

    // 16 slots: s<8 A-plane rows, s>=8 B-plane rows; wave w owns s=w*4..+3
    int off0[4]; const ushort* srcp[4];
#pragma unroll
    for (int i = 0; i < 4; ++i) {
        int s = w * 4 + i;
        if (s < 8) {
            int ml = s * 8 + (lane >> 3);
            int mm = m0 + ml;
            int b_ = mm >> 8, cell = mm & 255, px0 = cell >> 4, py0 = cell & 15;
            off0[i] = ((b_ * CP + px0 + 1) * CP + py0 + 1) * NAT + u * 8;
            srcp[i] = rp;
        } else {
            int ml = (s - 8) * 8 + (lane >> 3);
            off0[i] = ml * 512 + u * 8;
            srcp[i] = w2h;
        }
    }
    auto stage = [&](int kc, int buf) {
        int ij = kc >> 1;
        int dA = (kc & 1) * 64 - ((ij >> 1) * CP + (ij & 1)) * NAT;
        int dB = kc * 64;
        uint4* base = lds + buf * 1024;
#pragma unroll
        for (int i = 0; i < 4; ++i) {
            int s = w * 4 + i;
            GLOAD16(srcp[i] + off0[i] + (s < 8 ? dA : dB), base + s * 64);
        }
    };

    f32x16 acc = {};
    const int arow = wm * 32 + (lane & 31);
    const int brow = wn * 32 + (lane & 31);
    const int ax = lane & 7;     // = arow&7 = brow&7

    stage(0, 0); stage(1, 1); stage(2, 2);
    for (int kc = 0; kc < 8; ++kc) {
        if (kc < 5) stage(kc + 3, (kc + 3) & 3);
        int nf = 7 - kc; nf = nf > 3 ? 3 : nf;    // chunks in flight past kc
        switch (nf) {
            case 3: asm volatile("s_waitcnt vmcnt(12)" ::: "memory"); break;
            case 2: asm volatile("s_waitcnt vmcnt(8)"  ::: "memory"); break;
            case 1: asm volatile("s_waitcnt vmcnt(4)"  ::: "memory"); break;
            default: asm volatile("s_waitcnt vmcnt(0)" ::: "memory"); break;
        }
        __builtin_amdgcn_s_barrier();            // chunk kc resident for all waves
        __builtin_amdgcn_sched_barrier(0);
        const uint4* Lb = lds + (kc & 3) * 1024;
#pragma unroll
        for (int ks = 0; ks < 4; ++ks) {
            int un = (ks * 2 + g) ^ ax;
            bf16x8 Ah = __builtin_bit_cast(bf16x8, Lb[      arow * 8 + un]);
            bf16x8 Bh = __builtin_bit_cast(bf16x8, Lb[512 + brow * 8 + un]);
            acc = __builtin_amdgcn_mfma_f32_32x32x16_bf16(Ah, Bh, acc, 0, 0, 0);
        }
        __builtin_amdgcn_sched_barrier(0);
        __builtin_amdgcn_s_barrier();            // buf free for overwrite
    }

    // ---- epilogue: stage 32x128 image slab in LDS, write resid coalesced ----
    float* ldsO = (float*)lds;            // [32][129] fp32
    const int uvx = wn * 32 + (lane & 31);
    const int uu = uvx >> 3, vv = uvx & 7;
#pragma unroll
    for (int r = 0; r < 16; ++r) {
        int mr = m0 + wm * 32 + (r & 3) + 8 * (r >> 2) + 4 * g;
        int cl = mr & 255;
        ldsO[(((cl >> 4) & 3) * 8 + uu) * 129 + (cl & 15) * 8 + vv] = acc[r];
    }
    __syncthreads();
    const int b0 = m0 >> 8;
    const int x0 = ((m0 & 255) >> 4) * 8;
    const int row = tid >> 3, c0 = (tid & 7) * 16;
    const int base = b0 * DIM * DIM + (x0 + row) * DIM + c0;
    const float* lrow = &ldsO[row * 129 + c0];
    uint hw[8];
#pragma unroll
    for (int v = 0; v < 4; ++v) {
        float4 im = *(const float4*)&img[base + v * 4];
        hw[v*2+0] = pk(f2bf(im.x - lrow[v*4+0]), f2bf(im.y - lrow[v*4+1]));
        hw[v*2+1] = pk(f2bf(im.z - lrow[v*4+2]), f2bf(im.w - lrow[v*4+3]));
    }
    *(uint4*)&rsh[base]     = uint4{hw[0],hw[1],hw[2],hw[3]};
    *(uint4*)&rsh[base + 8] = uint4{hw[4],hw[5],hw[6],hw[7]};
}

// grad: pure-bf16 GEMM g[m=64 cells, n=64 atoms] = resid[m,256] x Wthi^T.
// Depth-2 prefetch: 3 LDS bufs, counted vmcnt, raw barriers.
// R state is a SINGLE bf16 plane: RMW reads/writes one uint4 per 8 atoms.
__global__ __launch_bounds__(256) void kgrad(
    const ushort* __restrict__ rsh, const ushort* __restrict__ wth,
    ushort* __restrict__ rp,
    float* __restrict__ partials, const int* __restrict__ flags, int t)
{
    if (flags[t]) return;
    __shared__ uint4 lds[3072];   // 3 bufs x {A[512],B[512]} = 48 KB
    __shared__ float red0[16];
    const int tid = threadIdx.x;
    const int bx = blockIdx.x;
    const int xcd = bx & 7;   // bijective XCD swizzle for nwg=450 (q=56,r=2)
    const int bid = (xcd < 2 ? xcd * 57 : 114 + (xcd - 2) * 56) + (bx >> 3);
    const int m0 = bid * 64;
    const int n0 = blockIdx.y * 64;
    const int lane = tid & 63, w = tid >> 6;
    const int wm = w >> 1, wn = w & 1, g = lane >> 5;
    const int u = (lane & 7) ^ ((lane >> 3) & 7);

    int off0[4]; const ushort* srcp[4];
#pragma unroll
    for (int i = 0; i < 4; ++i) {
        int s = w * 4 + i;
        if (s < 8) {
            int ml = s * 8 + (lane >> 3);
            int mA = m0 + ml, bA = mA / 225, rm = mA % 225, px = rm / 15, py = rm % 15;
            off0[i] = bA * DIM * DIM + (8 * px + (u >> 1)) * DIM + 8 * py + (u & 1) * 8;
            srcp[i] = rsh;
        } else {
            int ml = (s - 8) * 8 + (lane >> 3);
            off0[i] = (n0 + ml) * 256 + u * 8;
            srcp[i] = wth;
        }
    }
    auto stage = [&](int kc, int buf) {
        uint4* base = lds + buf * 1024;
#pragma unroll
        for (int i = 0; i < 4; ++i) {
            int s = w * 4 + i;
            GLOAD16(srcp[i] + off0[i] + (s < 8 ? kc * 512 : kc * 64), base + s * 64);
        }
    };

    f32x16 acc = {};
    const int arow = wm * 32 + (lane & 31);
    const int brow = wn * 32 + (lane & 31);
    const int ax = lane & 7;

    stage(0, 0); stage(1, 1);
    for (int kc = 0; kc < 4; ++kc) {
        if (kc < 2) stage(kc + 2, (kc + 2) % 3);
        int nf = 3 - kc; nf = nf > 2 ? 2 : nf;
        switch (nf) {
            case 2: asm volatile("s_waitcnt vmcnt(8)" ::: "memory"); break;
            case 1: asm volatile("s_waitcnt vmcnt(4)" ::: "memory"); break;
            default: asm volatile("s_waitcnt vmcnt(0)" ::: "memory"); break;
        }
        __builtin_amdgcn_s_barrier();
        __builtin_amdgcn_sched_barrier(0);
        const uint4* Lb = lds + (kc % 3) * 1024;
#pragma unroll
        for (int ks = 0; ks < 4; ++ks) {
            int un = (ks * 2 + g) ^ ax;
            bf16x8 Ah = __builtin_bit_cast(bf16x8, Lb[      arow * 8 + un]);
            bf16x8 Bh = __builtin_bit_cast(bf16x8, Lb[512 + brow * 8 + un]);
            acc = __builtin_amdgcn_mfma_f32_32x32x16_bf16(Ah, Bh, acc, 0, 0, 0);
        }
        __builtin_amdgcn_sched_barrier(0);
        __builtin_amdgcn_s_barrier();
    }

    // ---- stage acc -> ldsO[64][76] (<=2-way conflicts both phases)
    float* ldsO = (float*)lds;
    {
        const int colL = wn * 32 + (lane & 31);
#pragma unroll
        for (int r = 0; r < 16; ++r) {
            int rowL = wm * 32 + (r & 3) + 8 * (r >> 2) + 4 * g;
            ldsO[rowL * 76 + colL] = acc[r];
        }
    }
    __syncthreads();

    // ---- vectorized RMW on single-plane R: 2 items/thread, 8 atoms each
    float d2 = 0.f, r2 = 0.f;
#pragma unroll
    for (int i = 0; i < 2; ++i) {
        int item = i * 256 + tid;
        int rowL = item >> 3, ch = item & 7;
        int mr = m0 + rowL;
        int bb = mr / 225, rm = mr % 225, pxx = rm / 15, pyy = rm % 15;
        int base = ((bb * CP + pxx + 1) * CP + pyy + 1) * NAT + n0 + ch * 8;
        uint4 hv = *(const uint4*)&rp[base];
        const float* lp = &ldsO[rowL * 76 + ch * 8];
        uint ho[4];
#pragma unroll
        for (int wd = 0; wd < 4; ++wd) {
            uint hw_ = ((const uint*)&hv)[wd];
            ushort nh0, nh1;
            {
                float rold = us2f((ushort)hw_);
                float v = fmaf(STEP, lp[wd * 2 + 0], rold);
                float st = fmaxf(v - LMD, 0.f) - fmaxf(-v - LMD, 0.f);
                nh0 = f2bf(st);
                float df = us2f(nh0) - rold;      // stored-state delta
                d2 += df * df; r2 += rold * rold;
            }
            {
                float rold = us2f((ushort)(hw_ >> 16));
                float v = fmaf(STEP, lp[wd * 2 + 1], rold);
                float st = fmaxf(v - LMD, 0.f) - fmaxf(-v - LMD, 0.f);
                nh1 = f2bf(st);
                float df = us2f(nh1) - rold;
                d2 += df * df; r2 += rold * rold;
            }
            ho[wd] = pk(nh0, nh1);
        }
        *(uint4*)&rp[base] = uint4{ho[0], ho[1], ho[2], ho[3]};
    }

    for (int off = 32; off; off >>= 1) { d2 += __shfl_down(d2, off, 64); r2 += __shfl_down(r2, off, 64); }
    int w_ = tid >> 6, l = tid & 63;
    if (l == 0) { red0[w_] = d2; red0[8 + w_] = r2; }
    __syncthreads();
    if (tid == 0) {
        float td = red0[0] + red0[1] + red0[2] + red0[3];
        float tr = red0[8] + red0[9] + red0[10] + red0[11];
        int pb2 = blockIdx.y * 450 + bid;
        partials[pb2] = td;
        partials[1024 + pb2] = tr;
    }
}

// final reconstruction: C = R x (W2hi + W2lo)^T, fp32 out.
// 3 planes staged (R, Bh, Bl), simple double-buffer.
__global__ __launch_bounds__(256) void kfinal(
    const ushort* __restrict__ rp,
    const ushort* __restrict__ w2h, const ushort* __restrict__ w2l,
    float* __restrict__ outp)
{
    const int tid = threadIdx.x;
    __shared__ uint4 lds[3072];   // 2 bufs x {A[512],Bh[512],Bl[512]} = 48 KB
    const int bx = blockIdx.x;
    const int bid = ((bx & 7) << 6) | (bx >> 3);
    const int m0 = bid * 64;
    const int lane = tid & 63, w = tid >> 6;
    const int wm = w >> 1, wn = w & 1, g = lane >> 5;
    const int u = (lane & 7) ^ ((lane >> 3) & 7);

    // 24 slots: 0-7 A rows, 8-15 Bh rows, 16-23 Bl rows; wave w owns w*6..+5
    const ushort* const srcs[3] = {rp, w2h, w2l};
    int off0[6]; const ushort* srcp[6];
#pragma unroll
    for (int i = 0; i < 6; ++i) {
        int j = w * 6 + i, p = j >> 3, jj = j & 7;
        int ml = jj * 8 + (lane >> 3);
        srcp[i] = srcs[p];
        if (p == 0) {
            int mm = m0 + ml;
            int b_ = mm >> 8, cell = mm & 255, px0 = cell >> 4, py0 = cell & 15;
            off0[i] = ((b_ * CP + px0 + 1) * CP + py0 + 1) * NAT + u * 8;
        } else {
            off0[i] = ml * 512 + u * 8;
        }
    }
    auto stage = [&](int kc, int buf) {
        int ij = kc >> 1;
        int dA = (kc & 1) * 64 - ((ij >> 1) * CP + (ij & 1)) * NAT;
        int dB = kc * 64;
#pragma unroll
        for (int i = 0; i < 6; ++i) {
            int j = w * 6 + i;
            GLOAD16(srcp[i] + off0[i] + (j < 8 ? dA : dB), lds + buf * 1536 + j * 64);
        }
    };

    f32x16 acc = {};
    const int arow = wm * 32 + (lane & 31);
    const int brow = wn * 32 + (lane & 31);
    const int ax = lane & 7;

    stage(0, 0);
    __syncthreads();
    for (int kc = 0;; ++kc) {
        const int cur = kc & 1;
        if (kc < 7) stage(kc + 1, cur ^ 1);
        const uint4* Lb = lds + cur * 1536;
#pragma unroll
        for (int ks = 0; ks < 4; ++ks) {
            int un = (ks * 2 + g) ^ ax;
            bf16x8 Ah = __builtin_bit_cast(bf16x8, Lb[       arow * 8 + un]);
            bf16x8 Bh = __builtin_bit_cast(bf16x8, Lb[512  + brow * 8 + un]);
            bf16x8 Bl = __builtin_bit_cast(bf16x8, Lb[1024 + brow * 8 + un]);
            acc = __builtin_amdgcn_mfma_f32_32x32x16_bf16(Ah, Bh, acc, 0, 0, 0);
            acc = __builtin_amdgcn_mfma_f32_32x32x16_bf16(Ah, Bl, acc, 0, 0, 0);
        }
        if (kc == 7) break;
        __syncthreads();
    }

    __syncthreads();
    float* ldsO = (float*)lds;
    const int uvx = wn * 32 + (lane & 31);
    const int uu = uvx >> 3, vv = uvx & 7;
#pragma unroll
    for (int r = 0; r < 16; ++r) {
        int mr = m0 + wm * 32 + (r & 3) + 8 * (r >> 2) + 4 * g;
        int cl = mr & 255;
        ldsO[(((cl >> 4) & 3) * 8 + uu) * 129 + (cl & 15) * 8 + vv] = acc[r];
    }
    __syncthreads();
    const int b0 = m0 >> 8;
    const int x0 = ((m0 & 255) >> 4) * 8;
    const int row = tid >> 3, c0 = (tid & 7) * 16;
    const int base = b0 * DIM * DIM + (x0 + row) * DIM + c0;
    const float* lrow = &ldsO[row * 129 + c0];
#pragma unroll
    for (int v = 0; v < 4; ++v)
        *(float4*)&outp[base + v * 4] =
            float4{lrow[v*4], lrow[v*4+1], lrow[v*4+2], lrow[v*4+3]};
}

extern "C" void kernel_launch(void* const* d_in, const int* in_sizes, int n_in,
                              void* d_out, int out_size, void* d_ws, size_t ws_size,
                              hipStream_t stream) {
    const float* img = (const float*)d_in[0];
    const float* W   = (const float*)d_in[1];
    char* ws = (char*)d_ws;
    ushort* rp  = (ushort*)(ws + O_RP);
    ushort* rsh = (ushort*)(ws + O_RSH);
    ushort* w2h = (ushort*)(ws + O_W2H);
    ushort* w2l = (ushort*)(ws + O_W2L);
    ushort* wth = (ushort*)(ws + O_WTH);
    ushort* wtl = (ushort*)(ws + O_WTL);
    float* partials = (float*)(ws + O_PART);
    int*   flags    = (int*)(ws + O_FLAG);
    float* outp = (float*)d_out;

    kzero<<<2312, 256, 0, stream>>>((uint4*)(ws + O_RP), flags);  // R plane = 9.47 MB
    kprep<<<128, 256, 0, stream>>>(W, wth, wtl, w2h, w2l);
    kinit0<<<1024, 256, 0, stream>>>(img, rsh);                   // t=0: resid = img
    kgrad<<<dim3(450, 2), 256, 0, stream>>>(rsh, wth, rp, partials, flags, 0);
    for (int t = 1; t < MAXIT; ++t) {
        kconvt<<<512, 256, 0, stream>>>(rp, w2h, img, rsh, partials, flags, t);
        kgrad<<<dim3(450, 2), 256, 0, stream>>>(rsh, wth, rp, partials, flags, t);
    }
    kfinal<<<512, 256, 0, stream>>>(rp, w2h, w2l, outp);
}

// Round 11
// 439.876 us; speedup vs baseline: 2.3839x; 1.0291x over previous
//
#include <hip/hip_runtime.h>
#include <stdint.h>

#define BATCH 128
#define NAT   128
#define DIM   128
#define CP    17
#define MAXIT 20
#define STEP  0.2f      // 2 * R_LR
#define LMD   0.005f
#define NGRAD 900

typedef short bf16x8 __attribute__((ext_vector_type(8)));   // 8 bf16 (4 VGPR)
typedef float f32x16 __attribute__((ext_vector_type(16)));  // 32x32 C/D

#define SZ_RP (BATCH*CP*CP*NAT)     // 4,734,976 elems
#define SZ_RS (BATCH*DIM*DIM)       // 2,097,152 elems
// workspace byte offsets (all 16B-aligned). R = single bf16 plane.
#define O_RP   0
#define O_RSH  (O_RP + SZ_RP*2)
#define O_W2H  (O_RSH + SZ_RS*2)
#define O_W2L  (O_W2H + 64*512*2)
#define O_WTH  (O_W2L + 64*512*2)
#define O_WTL  (O_WTH + 128*256*2)
#define O_PART (O_WTL + 128*256*2)
#define O_FLAG (O_PART + 2048*4)

#define GLOAD16(gp, lp) __builtin_amdgcn_global_load_lds( \
    (const __attribute__((address_space(1))) uint32_t*)(gp), \
    (__attribute__((address_space(3))) uint32_t*)(lp), 16, 0, 0)

// split fp32 -> hi/lo bf16 (RNE)
__device__ __forceinline__ void split2(float x, ushort& h, ushort& l) {
    uint32_t u = __float_as_uint(x);
    uint32_t hr = (u + 0x7FFFu + ((u >> 16) & 1u)) >> 16;
    h = (ushort)hr;
    float r = x - __uint_as_float(hr << 16);
    uint32_t u2 = __float_as_uint(r);
    l = (ushort)((u2 + 0x7FFFu + ((u2 >> 16) & 1u)) >> 16);
}
__device__ __forceinline__ float us2f(ushort u) {
    return __uint_as_float(((uint32_t)u) << 16);
}
__device__ __forceinline__ uint pk(ushort a, ushort b) {
    return (uint)a | ((uint)b << 16);
}
__device__ __forceinline__ ushort f2bf(float x) {   // RNE round to bf16
    uint32_t u = __float_as_uint(x);
    return (ushort)((u + 0x7FFFu + ((u >> 16) & 1u)) >> 16);
}

__global__ void kzero(uint4* __restrict__ rp, int* __restrict__ flags) {
    int i = blockIdx.x * 256 + threadIdx.x;
    rp[i] = uint4{0u, 0u, 0u, 0u};   // R single plane
    if (blockIdx.x == 0 && threadIdx.x < 32) flags[threadIdx.x] = 0;
}

// WtT = W layout [n][256]; W2T[uv][ij*128+n]; both as hi/lo bf16 planes
__global__ void kprep(const float* __restrict__ W,
                      ushort* __restrict__ wth, ushort* __restrict__ wtl,
                      ushort* __restrict__ w2h, ushort* __restrict__ w2l) {
    int tid = blockIdx.x * 256 + threadIdx.x;   // 32768
    int n = tid >> 8, kk = tid & 255;
    ushort h, l; split2(W[tid], h, l);
    wth[tid] = h; wtl[tid] = l;
    int kx = kk >> 4, ky = kk & 15;
    int uv = (kx & 7) * 8 + (ky & 7);
    int k2 = ((kx >> 3) * 2 + (ky >> 3)) * 128 + n;
    w2h[uv * 512 + k2] = h; w2l[uv * 512 + k2] = l;
}

// t=0 shortcut: R==0 -> resid = img (single bf16 plane)
__global__ void kinit0(const float* __restrict__ img, ushort* __restrict__ rsh) {
    int t8 = (blockIdx.x * 256 + threadIdx.x) * 8;
    uint hw[4];
#pragma unroll
    for (int v = 0; v < 2; ++v) {
        float4 im = *(const float4*)&img[t8 + v * 4];
        hw[v*2+0] = pk(f2bf(im.x), f2bf(im.y));
        hw[v*2+1] = pk(f2bf(im.z), f2bf(im.w));
    }
    *(uint4*)&rsh[t8] = uint4{hw[0],hw[1],hw[2],hw[3]};
}

// resid kconvt: pure-bf16 GEMM C[m=cell,uv] = R[m,512] x W2hi^T.
// Depth-3 prefetch: 4 LDS bufs, counted vmcnt, raw barriers.
// T14: img epilogue operand prefetched at kernel entry.
__global__ __launch_bounds__(256) void kconvt(
    const ushort* __restrict__ rp, const ushort* __restrict__ w2h,
    const float* __restrict__ img, ushort* __restrict__ rsh,
    const float* __restrict__ partials, int* __restrict__ flags, int t)
{
    const int tid = threadIdx.x;
    {   // convergence gate (deterministic, same in every block)
        __shared__ float red0[16];
        __shared__ int sgate;
        float d2 = 0.f, r2 = 0.f;
        for (int i = tid; i < NGRAD; i += 256) { d2 += partials[i]; r2 += partials[1024 + i]; }
        for (int off = 32; off; off >>= 1) { d2 += __shfl_down(d2, off, 64); r2 += __shfl_down(r2, off, 64); }
        int w_ = tid >> 6, l = tid & 63;
        if (l == 0) { red0[w_] = d2; red0[8 + w_] = r2; }
        __syncthreads();
        if (tid == 0) {
            float td = red0[0] + red0[1] + red0[2] + red0[3];
            float tr = red0[8] + red0[9] + red0[10] + red0[11];
            sgate = flags[t - 1] | ((td < 1e-4f * tr) ? 1 : 0);
            if (blockIdx.x == 0) flags[t] = sgate;
        }
        __syncthreads();
        if (sgate) return;
    }

    __shared__ uint4 lds[4096];   // 4 bufs x {A[512],B[512]} = 64 KB
    const int bx = blockIdx.x;
    const int bid = ((bx & 7) << 6) | (bx >> 3);   // XCD swizzle, 512%8==0
    const int m0 = bid * 64;
    const int lane = tid & 63, w = tid >> 6;
    const int wm = w >> 1, wn = w & 1, g = lane >> 5;
    const int u = (lane & 7) ^ ((lane >> 3) & 7);   // pre-swizzled source unit

    // ---- T14 early prefetch of the epilogue img slab (consumed at end) ----
    const int b0 = m0 >> 8;
    const int x0 = ((m0 & 255) >> 4) * 8;
    const int erow = tid >> 3, ec0 = (tid & 7) * 16;
    const int ebase = b0 * DIM * DIM + (x0 + erow) * DIM + ec0;
    float4 im0 = *(const float4*)&img[ebase];
    float4 im1 = *(const float4*)&img[ebase + 4];
    float4 im2 = *(const float4*)&img[ebase + 8];
    float4 im3 = *(const float4*)&img[ebase + 12];
    __builtin_amdgcn_sched_barrier(0);   // pin: issued before staging

    // 16 slots: s<8 A-plane rows, s>=8 B-plane rows; wave w owns s=w*4..+3
    int off0[4]; const ushort* srcp[4];
#pragma unroll
    for (int i = 0; i < 4; ++i) {
        int s = w * 4 + i;
        if (s < 8) {
            int ml = s * 8 + (lane >> 3);
            int mm = m0 + ml;
            int b_ = mm >> 8, cell = mm & 255, px0 = cell >> 4, py0 = cell & 15;
            off0[i] = ((b_ * CP + px0 + 1) * CP + py0 + 1) * NAT + u * 8;
            srcp[i] = rp;
        } else {
            int ml = (s - 8) * 8 + (lane >> 3);
            off0[i] = ml * 512 + u * 8;
            srcp[i] = w2h;
        }
    }
    auto stage = [&](int kc, int buf) {
        int ij = kc >> 1;
        int dA = (kc & 1) * 64 - ((ij >> 1) * CP + (ij & 1)) * NAT;
        int dB = kc * 64;
        uint4* base = lds + buf * 1024;
#pragma unroll
        for (int i = 0; i < 4; ++i) {
            int s = w * 4 + i;
            GLOAD16(srcp[i] + off0[i] + (s < 8 ? dA : dB), base + s * 64);
        }
    };

    f32x16 acc = {};
    const int arow = wm * 32 + (lane & 31);
    const int brow = wn * 32 + (lane & 31);
    const int ax = lane & 7;     // = arow&7 = brow&7

    stage(0, 0); stage(1, 1); stage(2, 2);
    for (int kc = 0; kc < 8; ++kc) {
        if (kc < 5) stage(kc + 3, (kc + 3) & 3);
        int nf = 7 - kc; nf = nf > 3 ? 3 : nf;    // chunks in flight past kc
        switch (nf) {
            case 3: asm volatile("s_waitcnt vmcnt(12)" ::: "memory"); break;
            case 2: asm volatile("s_waitcnt vmcnt(8)"  ::: "memory"); break;
            case 1: asm volatile("s_waitcnt vmcnt(4)"  ::: "memory"); break;
            default: asm volatile("s_waitcnt vmcnt(0)" ::: "memory"); break;
        }
        __builtin_amdgcn_s_barrier();            // chunk kc resident for all waves
        __builtin_amdgcn_sched_barrier(0);
        const uint4* Lb = lds + (kc & 3) * 1024;
#pragma unroll
        for (int ks = 0; ks < 4; ++ks) {
            int un = (ks * 2 + g) ^ ax;
            bf16x8 Ah = __builtin_bit_cast(bf16x8, Lb[      arow * 8 + un]);
            bf16x8 Bh = __builtin_bit_cast(bf16x8, Lb[512 + brow * 8 + un]);
            acc = __builtin_amdgcn_mfma_f32_32x32x16_bf16(Ah, Bh, acc, 0, 0, 0);
        }
        __builtin_amdgcn_sched_barrier(0);
        __builtin_amdgcn_s_barrier();            // buf free for overwrite
    }

    // ---- epilogue: stage 32x128 slab in LDS, write resid coalesced ----
    float* ldsO = (float*)lds;            // [32][129] fp32
    const int uvx = wn * 32 + (lane & 31);
    const int uu = uvx >> 3, vv = uvx & 7;
#pragma unroll
    for (int r = 0; r < 16; ++r) {
        int mr = m0 + wm * 32 + (r & 3) + 8 * (r >> 2) + 4 * g;
        int cl = mr & 255;
        ldsO[(((cl >> 4) & 3) * 8 + uu) * 129 + (cl & 15) * 8 + vv] = acc[r];
    }
    __syncthreads();
    const float* lrow = &ldsO[erow * 129 + ec0];
    uint hw[8];
    hw[0] = pk(f2bf(im0.x - lrow[0]),  f2bf(im0.y - lrow[1]));
    hw[1] = pk(f2bf(im0.z - lrow[2]),  f2bf(im0.w - lrow[3]));
    hw[2] = pk(f2bf(im1.x - lrow[4]),  f2bf(im1.y - lrow[5]));
    hw[3] = pk(f2bf(im1.z - lrow[6]),  f2bf(im1.w - lrow[7]));
    hw[4] = pk(f2bf(im2.x - lrow[8]),  f2bf(im2.y - lrow[9]));
    hw[5] = pk(f2bf(im2.z - lrow[10]), f2bf(im2.w - lrow[11]));
    hw[6] = pk(f2bf(im3.x - lrow[12]), f2bf(im3.y - lrow[13]));
    hw[7] = pk(f2bf(im3.z - lrow[14]), f2bf(im3.w - lrow[15]));
    *(uint4*)&rsh[ebase]     = uint4{hw[0],hw[1],hw[2],hw[3]};
    *(uint4*)&rsh[ebase + 8] = uint4{hw[4],hw[5],hw[6],hw[7]};
}

// grad: pure-bf16 GEMM g[m=64 cells, n=64 atoms] = resid[m,256] x Wthi^T.
// Depth-2 prefetch: 3 LDS bufs, counted vmcnt, raw barriers.
// T14: R-state for the RMW prefetched at kernel entry (hidden under K-loop).
__global__ __launch_bounds__(256) void kgrad(
    const ushort* __restrict__ rsh, const ushort* __restrict__ wth,
    ushort* __restrict__ rp,
    float* __restrict__ partials, const int* __restrict__ flags, int t)
{
    if (flags[t]) return;
    __shared__ uint4 lds[3072];   // 3 bufs x {A[512],B[512]} = 48 KB
    __shared__ float red0[16];
    const int tid = threadIdx.x;
    const int bx = blockIdx.x;
    const int xcd = bx & 7;   // bijective XCD swizzle for nwg=450 (q=56,r=2)
    const int bid = (xcd < 2 ? xcd * 57 : 114 + (xcd - 2) * 56) + (bx >> 3);
    const int m0 = bid * 64;
    const int n0 = blockIdx.y * 64;
    const int lane = tid & 63, w = tid >> 6;
    const int wm = w >> 1, wn = w & 1, g = lane >> 5;
    const int u = (lane & 7) ^ ((lane >> 3) & 7);

    // ---- T14 early prefetch of R state (consumed by the RMW epilogue) ----
    int rbase0, rbase1; uint4 rv0, rv1;
    {
        int item = tid;
        int rowL = item >> 3, ch = item & 7;
        int mr = m0 + rowL;
        int bb = mr / 225, rm = mr % 225, pxx = rm / 15, pyy = rm % 15;
        rbase0 = ((bb * CP + pxx + 1) * CP + pyy + 1) * NAT + n0 + ch * 8;
        rv0 = *(const uint4*)&rp[rbase0];
    }
    {
        int item = 256 + tid;
        int rowL = item >> 3, ch = item & 7;
        int mr = m0 + rowL;
        int bb = mr / 225, rm = mr % 225, pxx = rm / 15, pyy = rm % 15;
        rbase1 = ((bb * CP + pxx + 1) * CP + pyy + 1) * NAT + n0 + ch * 8;
        rv1 = *(const uint4*)&rp[rbase1];
    }
    __builtin_amdgcn_sched_barrier(0);   // pin: issued before staging

    int off0[4]; const ushort* srcp[4];
#pragma unroll
    for (int i = 0; i < 4; ++i) {
        int s = w * 4 + i;
        if (s < 8) {
            int ml = s * 8 + (lane >> 3);
            int mA = m0 + ml, bA = mA / 225, rm = mA % 225, px = rm / 15, py = rm % 15;
            off0[i] = bA * DIM * DIM + (8 * px + (u >> 1)) * DIM + 8 * py + (u & 1) * 8;
            srcp[i] = rsh;
        } else {
            int ml = (s - 8) * 8 + (lane >> 3);
            off0[i] = (n0 + ml) * 256 + u * 8;
            srcp[i] = wth;
        }
    }
    auto stage = [&](int kc, int buf) {
        uint4* base = lds + buf * 1024;
#pragma unroll
        for (int i = 0; i < 4; ++i) {
            int s = w * 4 + i;
            GLOAD16(srcp[i] + off0[i] + (s < 8 ? kc * 512 : kc * 64), base + s * 64);
        }
    };

    f32x16 acc = {};
    const int arow = wm * 32 + (lane & 31);
    const int brow = wn * 32 + (lane & 31);
    const int ax = lane & 7;

    stage(0, 0); stage(1, 1);
    for (int kc = 0; kc < 4; ++kc) {
        if (kc < 2) stage(kc + 2, (kc + 2) % 3);
        int nf = 3 - kc; nf = nf > 2 ? 2 : nf;
        switch (nf) {
            case 2: asm volatile("s_waitcnt vmcnt(8)" ::: "memory"); break;
            case 1: asm volatile("s_waitcnt vmcnt(4)" ::: "memory"); break;
            default: asm volatile("s_waitcnt vmcnt(0)" ::: "memory"); break;
        }
        __builtin_amdgcn_s_barrier();
        __builtin_amdgcn_sched_barrier(0);
        const uint4* Lb = lds + (kc % 3) * 1024;
#pragma unroll
        for (int ks = 0; ks < 4; ++ks) {
            int un = (ks * 2 + g) ^ ax;
            bf16x8 Ah = __builtin_bit_cast(bf16x8, Lb[      arow * 8 + un]);
            bf16x8 Bh = __builtin_bit_cast(bf16x8, Lb[512 + brow * 8 + un]);
            acc = __builtin_amdgcn_mfma_f32_32x32x16_bf16(Ah, Bh, acc, 0, 0, 0);
        }
        __builtin_amdgcn_sched_barrier(0);
        __builtin_amdgcn_s_barrier();
    }

    // ---- stage acc -> ldsO[64][76] (<=2-way conflicts both phases)
    float* ldsO = (float*)lds;
    {
        const int colL = wn * 32 + (lane & 31);
#pragma unroll
        for (int r = 0; r < 16; ++r) {
            int rowL = wm * 32 + (r & 3) + 8 * (r >> 2) + 4 * g;
            ldsO[rowL * 76 + colL] = acc[r];
        }
    }
    __syncthreads();

    // ---- RMW on prefetched R: 2 items/thread, 8 atoms each
    float d2 = 0.f, r2 = 0.f;
#pragma unroll
    for (int i = 0; i < 2; ++i) {
        int item = i * 256 + tid;
        int rowL = item >> 3, ch = item & 7;
        uint4 hv = i ? rv1 : rv0;
        int base = i ? rbase1 : rbase0;
        const float* lp = &ldsO[rowL * 76 + ch * 8];
        uint ho[4];
#pragma unroll
        for (int wd = 0; wd < 4; ++wd) {
            uint hw_ = ((const uint*)&hv)[wd];
            ushort nh0, nh1;
            {
                float rold = us2f((ushort)hw_);
                float v = fmaf(STEP, lp[wd * 2 + 0], rold);
                float st = fmaxf(v - LMD, 0.f) - fmaxf(-v - LMD, 0.f);
                nh0 = f2bf(st);
                float df = us2f(nh0) - rold;      // stored-state delta
                d2 += df * df; r2 += rold * rold;
            }
            {
                float rold = us2f((ushort)(hw_ >> 16));
                float v = fmaf(STEP, lp[wd * 2 + 1], rold);
                float st = fmaxf(v - LMD, 0.f) - fmaxf(-v - LMD, 0.f);
                nh1 = f2bf(st);
                float df = us2f(nh1) - rold;
                d2 += df * df; r2 += rold * rold;
            }
            ho[wd] = pk(nh0, nh1);
        }
        *(uint4*)&rp[base] = uint4{ho[0], ho[1], ho[2], ho[3]};
    }

    for (int off = 32; off; off >>= 1) { d2 += __shfl_down(d2, off, 64); r2 += __shfl_down(r2, off, 64); }
    int w_ = tid >> 6, l = tid & 63;
    if (l == 0) { red0[w_] = d2; red0[8 + w_] = r2; }
    __syncthreads();
    if (tid == 0) {
        float td = red0[0] + red0[1] + red0[2] + red0[3];
        float tr = red0[8] + red0[9] + red0[10] + red0[11];
        int pb2 = blockIdx.y * 450 + bid;
        partials[pb2] = td;
        partials[1024 + pb2] = tr;
    }
}

// final reconstruction: C = R x (W2hi + W2lo)^T, fp32 out.
__global__ __launch_bounds__(256) void kfinal(
    const ushort* __restrict__ rp,
    const ushort* __restrict__ w2h, const ushort* __restrict__ w2l,
    float* __restrict__ outp)
{
    const int tid = threadIdx.x;
    __shared__ uint4 lds[3072];   // 2 bufs x {A[512],Bh[512],Bl[512]} = 48 KB
    const int bx = blockIdx.x;
    const int bid = ((bx & 7) << 6) | (bx >> 3);
    const int m0 = bid * 64;
    const int lane = tid & 63, w = tid >> 6;
    const int wm = w >> 1, wn = w & 1, g = lane >> 5;
    const int u = (lane & 7) ^ ((lane >> 3) & 7);

    // 24 slots: 0-7 A rows, 8-15 Bh rows, 16-23 Bl rows; wave w owns w*6..+5
    const ushort* const srcs[3] = {rp, w2h, w2l};
    int off0[6]; const ushort* srcp[6];
#pragma unroll
    for (int i = 0; i < 6; ++i) {
        int j = w * 6 + i, p = j >> 3, jj = j & 7;
        int ml = jj * 8 + (lane >> 3);
        srcp[i] = srcs[p];
        if (p == 0) {
            int mm = m0 + ml;
            int b_ = mm >> 8, cell = mm & 255, px0 = cell >> 4, py0 = cell & 15;
            off0[i] = ((b_ * CP + px0 + 1) * CP + py0 + 1) * NAT + u * 8;
        } else {
            off0[i] = ml * 512 + u * 8;
        }
    }
    auto stage = [&](int kc, int buf) {
        int ij = kc >> 1;
        int dA = (kc & 1) * 64 - ((ij >> 1) * CP + (ij & 1)) * NAT;
        int dB = kc * 64;
#pragma unroll
        for (int i = 0; i < 6; ++i) {
            int j = w * 6 + i;
            GLOAD16(srcp[i] + off0[i] + (j < 8 ? dA : dB), lds + buf * 1536 + j * 64);
        }
    };

    f32x16 acc = {};
    const int arow = wm * 32 + (lane & 31);
    const int brow = wn * 32 + (lane & 31);
    const int ax = lane & 7;

    stage(0, 0);
    __syncthreads();
    for (int kc = 0;; ++kc) {
        const int cur = kc & 1;
        if (kc < 7) stage(kc + 1, cur ^ 1);
        const uint4* Lb = lds + cur * 1536;
#pragma unroll
        for (int ks = 0; ks < 4; ++ks) {
            int un = (ks * 2 + g) ^ ax;
            bf16x8 Ah = __builtin_bit_cast(bf16x8, Lb[       arow * 8 + un]);
            bf16x8 Bh = __builtin_bit_cast(bf16x8, Lb[512  + brow * 8 + un]);
            bf16x8 Bl = __builtin_bit_cast(bf16x8, Lb[1024 + brow * 8 + un]);
            acc = __builtin_amdgcn_mfma_f32_32x32x16_bf16(Ah, Bh, acc, 0, 0, 0);
            acc = __builtin_amdgcn_mfma_f32_32x32x16_bf16(Ah, Bl, acc, 0, 0, 0);
        }
        if (kc == 7) break;
        __syncthreads();
    }

    __syncthreads();
    float* ldsO = (float*)lds;
    const int uvx = wn * 32 + (lane & 31);
    const int uu = uvx >> 3, vv = uvx & 7;
#pragma unroll
    for (int r = 0; r < 16; ++r) {
        int mr = m0 + wm * 32 + (r & 3) + 8 * (r >> 2) + 4 * g;
        int cl = mr & 255;
        ldsO[(((cl >> 4) & 3) * 8 + uu) * 129 + (cl & 15) * 8 + vv] = acc[r];
    }
    __syncthreads();
    const int b0 = m0 >> 8;
    const int x0 = ((m0 & 255) >> 4) * 8;
    const int row = tid >> 3, c0 = (tid & 7) * 16;
    const int base = b0 * DIM * DIM + (x0 + row) * DIM + c0;
    const float* lrow = &ldsO[row * 129 + c0];
#pragma unroll
    for (int v = 0; v < 4; ++v)
        *(float4*)&outp[base + v * 4] =
            float4{lrow[v*4], lrow[v*4+1], lrow[v*4+2], lrow[v*4+3]};
}

extern "C" void kernel_launch(void* const* d_in, const int* in_sizes, int n_in,
                              void* d_out, int out_size, void* d_ws, size_t ws_size,
                              hipStream_t stream) {
    const float* img = (const float*)d_in[0];
    const float* W   = (const float*)d_in[1];
    char* ws = (char*)d_ws;
    ushort* rp  = (ushort*)(ws + O_RP);
    ushort* rsh = (ushort*)(ws + O_RSH);
    ushort* w2h = (ushort*)(ws + O_W2H);
    ushort* w2l = (ushort*)(ws + O_W2L);
    ushort* wth = (ushort*)(ws + O_WTH);
    ushort* wtl = (ushort*)(ws + O_WTL);
    float* partials = (float*)(ws + O_PART);
    int*   flags    = (int*)(ws + O_FLAG);
    float* outp = (float*)d_out;

    kzero<<<2312, 256, 0, stream>>>((uint4*)(ws + O_RP), flags);  // R plane = 9.47 MB
    kprep<<<128, 256, 0, stream>>>(W, wth, wtl, w2h, w2l);
    kinit0<<<1024, 256, 0, stream>>>(img, rsh);                   // t=0: resid = img
    kgrad<<<dim3(450, 2), 256, 0, stream>>>(rsh, wth, rp, partials, flags, 0);
    for (int t = 1; t < MAXIT; ++t) {
        kconvt<<<512, 256, 0, stream>>>(rp, w2h, img, rsh, partials, flags, t);
        kgrad<<<dim3(450, 2), 256, 0, stream>>>(rsh, wth, rp, partials, flags, t);
    }
    kfinal<<<512, 256, 0, stream>>>(rp, w2h, w2l, outp);
}